// Round 8
// baseline (525.583 us; speedup 1.0000x reference)
//
#include <hip/hip_runtime.h>
#include <hip/hip_bf16.h>
#include <hip/hip_fp16.h>

#define NQ 10000
#define BS 6
#define NV 30825   // 23200 + 5800 + 1450 + 375

// vproj layout per batch (64B units = one head-row of 32ch bf16):
//   level l: unit = ubase[l] + (y*8 + h)*W + x   (x-adjacent => contiguous)
//   ubase: 0, 185600, 232000, 243600 ; per-batch 246600 units (15,782,400 B)

typedef __attribute__((ext_vector_type(8))) short bf16x8;
typedef __attribute__((ext_vector_type(8))) unsigned short u16x8;
typedef __attribute__((ext_vector_type(4))) float f32x4;
typedef __attribute__((ext_vector_type(2))) float f32x2;

__device__ __forceinline__ void gload_lds16(const void* g, void* l) {
  __builtin_amdgcn_global_load_lds(
      (const __attribute__((address_space(1))) unsigned int*)g,
      (__attribute__((address_space(3))) unsigned int*)l, 16, 0, 0);
}

__device__ __forceinline__ unsigned short bf_bits(float f) {
  __hip_bfloat16 h = __float2bfloat16(f);
  return *(unsigned short*)&h;
}
__device__ __forceinline__ float bfu(unsigned short u) {
  return __uint_as_float((unsigned)u << 16);
}

// ---------------------------------------------------------------------------
// Spatial sort key: (batch, 16x16 Morton cell of ref[z]).
// ---------------------------------------------------------------------------
__device__ __forceinline__ int item_key(const float* ref, int i) {
  int b = i / 40000;
  int rem = i - b * 40000;
  int q = rem >> 2, z = rem & 3;
  float2 rz = *(const float2*)(ref + (size_t)(b * NQ + q) * 8 + z * 2);
  int xq = min(max((int)(rz.x * 16.f), 0), 15);
  int yq = min(max((int)(rz.y * 16.f), 0), 15);
  int m = 0;
#pragma unroll
  for (int j = 0; j < 4; ++j)
    m |= (((xq >> j) & 1) << (2 * j)) | (((yq >> j) & 1) << (2 * j + 1));
  return b * 256 + m;
}

// ---------------------------------------------------------------------------
// Fused: pack+transpose weights to bf16 AND sort histogram (hist pre-zeroed
// by memset on the same stream).
// ---------------------------------------------------------------------------
__global__ __launch_bounds__(256) void prep_hist_kernel(
    const float* __restrict__ w_val, const float* __restrict__ w_off,
    const float* __restrict__ w_attn, const float* __restrict__ b_off,
    const float* __restrict__ b_attn, unsigned short* __restrict__ wvalT,
    unsigned short* __restrict__ wpackT, float* __restrict__ bpack,
    const float* __restrict__ ref, unsigned* __restrict__ hist) {
  int i = blockIdx.x * 256 + threadIdx.x;
  if (i < 65536) {
    int n = i >> 8, k = i & 255;
    wvalT[i] = bf_bits(w_val[k * 256 + n]);
  } else if (i < 262144) {
    int j = i - 65536;
    int n = j >> 8, k = j & 255;
    float v = (n < 512) ? w_off[k * 512 + n] : w_attn[k * 256 + (n - 512)];
    wpackT[j] = bf_bits(v);
  } else if (i < 262912) {
    int j = i - 262144;
    bpack[j] = (j < 512) ? b_off[j] : b_attn[j - 512];
  } else {
    int j = i - 262912;
    if (j < BS * NQ * 4) atomicAdd(&hist[item_key(ref, j)], 1u);
  }
}

// ---------------------------------------------------------------------------
// MFMA GEMM, fused A conversion, NT output-tiles per block (A read once per
// block instead of once per 128-col tile):
//   C[M, 128*NT*gridY](bf16) = bf16(A[M,256] f32) @ WT^T + bias
// 128-row tile, BK=64, 4 waves. As staged once per K-step and reused across
// NT B-tiles; Bs double-buffered via global_load_lds.
// ---------------------------------------------------------------------------
template <int NT, bool SCATTER>
__global__ __launch_bounds__(256) void gemm_mfma_kernel(
    const float* __restrict__ A, const unsigned short* __restrict__ WT,
    const float* __restrict__ bias, unsigned short* __restrict__ C, int M, int N) {
  __shared__ short As[128 * 64];
  __shared__ short Bs[2][128 * 64];
  const int tid = threadIdx.x;
  const int wv = tid >> 6;
  const int lane = tid & 63;
  const int wr = wv >> 1, wc = wv & 1;
  const int m0 = blockIdx.x * 128;
  const int n00 = blockIdx.y * (128 * NT);

  f32x4 acc[NT][4][4] = {};
  float4 ar[4][2];

  auto loadA = [&](int kt) {
#pragma unroll
    for (int j = 0; j < 4; ++j) {
      int u = j * 256 + tid;
      int row = u >> 3, oct = u & 7;
      int gr = m0 + row; if (gr >= M) gr = M - 1;
      const float4* ap = (const float4*)(A + (size_t)gr * 256 + kt * 64 + oct * 8);
      ar[j][0] = ap[0]; ar[j][1] = ap[1];
    }
  };
  auto writeA = [&]() {
#pragma unroll
    for (int j = 0; j < 4; ++j) {
      int u = j * 256 + tid;
      int row = u >> 3, oct = u & 7;
      float4 a0 = ar[j][0], a1 = ar[j][1];
      u16x8 pk = { bf_bits(a0.x), bf_bits(a0.y), bf_bits(a0.z), bf_bits(a0.w),
                   bf_bits(a1.x), bf_bits(a1.y), bf_bits(a1.z), bf_bits(a1.w) };
      *(u16x8*)&As[row * 64 + oct * 8] = pk;
    }
  };
  auto stageB = [&](int kt, int nt, int buf) {
#pragma unroll
    for (int j = 0; j < 4; ++j) {
      int u = j * 256 + tid;
      int row = u >> 3;
      int kbyte = (u & 7) * 16;
      int ldsoff = (j * 256 + wv * 64) * 16;
      gload_lds16((const char*)WT + (size_t)(n00 + nt * 128 + row) * 512 +
                      kt * 128 + kbyte,
                  (char*)Bs[buf] + ldsoff);
    }
  };

  loadA(0);
  stageB(0, 0, 0);
  writeA();
  __syncthreads();

  for (int kt = 0; kt < 4; ++kt) {
#pragma unroll
    for (int nt = 0; nt < NT; ++nt) {
      const int phase = kt * NT + nt;
      const int cur = phase & 1;
      // prefetch next phase's B tile
      int pnt = nt + 1, pkt = kt;
      if (pnt == NT) { pnt = 0; ++pkt; }
      if (pkt < 4) stageB(pkt, pnt, cur ^ 1);
      // prefetch next K-step's A regs early in this K-step
      if (nt == 0 && kt < 3) loadA(kt + 1);

      const short* bs = Bs[cur];
#pragma unroll
      for (int kk = 0; kk < 2; ++kk) {
        bf16x8 af[4], bfr[4];
#pragma unroll
        for (int mi = 0; mi < 4; ++mi) {
          int off = (wr * 64 + mi * 16 + (lane & 15)) * 64 + kk * 32 + (lane >> 4) * 8;
          af[mi] = *(const bf16x8*)&As[off];
        }
#pragma unroll
        for (int ni = 0; ni < 4; ++ni) {
          int off = (wc * 64 + ni * 16 + (lane & 15)) * 64 + kk * 32 + (lane >> 4) * 8;
          bfr[ni] = *(const bf16x8*)&bs[off];
        }
#pragma unroll
        for (int mi = 0; mi < 4; ++mi)
#pragma unroll
          for (int ni = 0; ni < 4; ++ni)
            acc[nt][mi][ni] = __builtin_amdgcn_mfma_f32_16x16x32_bf16(
                af[mi], bfr[ni], acc[nt][mi][ni], 0, 0, 0);
      }

      if (nt == NT - 1) {
        if (kt < 3) {
          __syncthreads();   // all As reads done; drains prefetched Bs gload
          writeA();          // As <- next K-step (regs already loaded)
          __syncthreads();   // new As + Bs visible
        }
      } else {
        __syncthreads();     // next Bs buffer ready
      }
    }
  }

#pragma unroll
  for (int nt = 0; nt < NT; ++nt) {
    const int colb = n00 + nt * 128 + wc * 64 + (lane & 15);
    float bvn[4];
#pragma unroll
    for (int ni = 0; ni < 4; ++ni) bvn[ni] = bias[colb + ni * 16];
#pragma unroll
    for (int mi = 0; mi < 4; ++mi) {
#pragma unroll
      for (int r = 0; r < 4; ++r) {
        int row = m0 + wr * 64 + mi * 16 + (lane >> 4) * 4 + r;
        if (row >= M) continue;
        if (!SCATTER) {
#pragma unroll
          for (int ni = 0; ni < 4; ++ni)
            C[(size_t)row * N + colb + ni * 16] = bf_bits(acc[nt][mi][ni][r] + bvn[ni]);
        } else {
          int b = row / NV;
          int pix = row - b * NV;
          int ubase, Wl, y, x;
          if (pix < 23200)      { int pl = pix;         y = pl / 200; x = pl - y * 200; ubase = 0;      Wl = 200; }
          else if (pix < 29000) { int pl = pix - 23200; y = pl / 100; x = pl - y * 100; ubase = 185600; Wl = 100; }
          else if (pix < 30450) { int pl = pix - 29000; y = pl / 50;  x = pl - y * 50;  ubase = 232000; Wl = 50;  }
          else                  { int pl = pix - 30450; y = pl / 25;  x = pl - y * 25;  ubase = 243600; Wl = 25;  }
          size_t bu = (size_t)b * 246600 + ubase + (size_t)(y * 8) * Wl + x;
#pragma unroll
          for (int ni = 0; ni < 4; ++ni) {
            int col = colb + ni * 16;
            int h = col >> 5, ch = col & 31;
            C[(bu + (size_t)h * Wl) * 32 + ch] = bf_bits(acc[nt][mi][ni][r] + bvn[ni]);
          }
        }
      }
    }
  }
}

// ---------------------------------------------------------------------------
// Sort: scan + scatter (hist built in prep_hist_kernel).
// ---------------------------------------------------------------------------
__global__ __launch_bounds__(256) void scan_kernel(unsigned* __restrict__ hist) {
  __shared__ unsigned sdata[256];
  int tid = threadIdx.x;
  unsigned v[6], sum = 0;
#pragma unroll
  for (int j = 0; j < 6; ++j) { v[j] = hist[tid * 6 + j]; sum += v[j]; }
  sdata[tid] = sum;
  __syncthreads();
  for (int d = 1; d < 256; d <<= 1) {
    unsigned t = (tid >= d) ? sdata[tid - d] : 0u;
    __syncthreads();
    sdata[tid] += t;
    __syncthreads();
  }
  unsigned excl = (tid > 0) ? sdata[tid - 1] : 0u;
#pragma unroll
  for (int j = 0; j < 6; ++j) { hist[tid * 6 + j] = excl; excl += v[j]; }
}

__global__ __launch_bounds__(256) void cell_scatter_kernel(
    const float* __restrict__ ref, unsigned* __restrict__ cursor,
    unsigned* __restrict__ perm) {
  int i = blockIdx.x * 256 + threadIdx.x;
  if (i >= BS * NQ * 4) return;
  unsigned pos = atomicAdd(&cursor[item_key(ref, i)], 1u);
  perm[pos] = (unsigned)i;
}

// ---------------------------------------------------------------------------
// Stage A: 4 waves/block, each wave = one sorted (b,q,z) item.
// Fused softmax + bilinear setup -> LDS; 8-lane cooperative 128B pair
// gathers; per-item 256-channel partial written non-atomically as f16.
// ---------------------------------------------------------------------------
__global__ __launch_bounds__(256) void msda_sample_kernel(
    const __hip_bfloat16* __restrict__ vproj,
    const __hip_bfloat16* __restrict__ C2,   // [BS*NQ,768]: 512 off | 256 attn
    const float* __restrict__ ref,
    const unsigned* __restrict__ perm,
    __half* __restrict__ partial) {          // [BS*NQ*4][256] f16
  const int tid = threadIdx.x;
  const int wv = tid >> 6, lane = tid & 63;
  const int sblk = (blockIdx.x & 7) * 7500 + (blockIdx.x >> 3);  // XCD swizzle
  const unsigned item = perm[sblk * 4 + wv];
  const int b = item / 40000;
  const int rem = item - b * 40000;
  const int q = rem >> 2, z = rem & 3;
  const int bq = b * NQ + q;

  __shared__ int   s_pidx[4][8][17];
  __shared__ float s_wsel[4][8][2][17];

  const int h = lane >> 3, sub = lane & 7;
  {
    // --- fused softmax: lane loads 4 logits [h*32 + sub*4 .. +4] ---
    ushort4 lg = *(const ushort4*)((const unsigned short*)C2 +
                                   (size_t)bq * 768 + 512 + lane * 4);
    float l0 = bfu(lg.x), l1 = bfu(lg.y), l2 = bfu(lg.z), l3 = bfu(lg.w);
    float mx = fmaxf(fmaxf(l0, l1), fmaxf(l2, l3));
    mx = fmaxf(mx, __shfl_xor(mx, 1));
    mx = fmaxf(mx, __shfl_xor(mx, 2));
    mx = fmaxf(mx, __shfl_xor(mx, 4));
    float e0 = __expf(l0 - mx), e1 = __expf(l1 - mx),
          e2 = __expf(l2 - mx), e3 = __expf(l3 - mx);
    float sm = e0 + e1 + e2 + e3;
    sm += __shfl_xor(sm, 1);
    sm += __shfl_xor(sm, 2);
    sm += __shfl_xor(sm, 4);
    float ez = (z == 0) ? e0 : (z == 1) ? e1 : (z == 2) ? e2 : e3;
    float aw = ez / sm;

    // --- bilinear setup for sample (h, l, p = z + 4*p2) ---
    const int l = sub >> 1, p2 = sub & 1, p = z + 4 * p2;
    __hip_bfloat162 ob = *(const __hip_bfloat162*)((const unsigned short*)C2 +
        (size_t)bq * 768 + (((h * 4 + l) * 8 + p) << 1));
    float ox = __bfloat162float(ob.x), oy = __bfloat162float(ob.y);
    float2 rz = *(const float2*)(ref + (size_t)bq * 8 + z * 2);

    const int W = (l == 0) ? 200 : (l == 1) ? 100 : (l == 2) ? 50 : 25;
    const int H = (l == 0) ? 116 : (l == 1) ? 58 : (l == 2) ? 29 : 15;
    const int ub = (l == 0) ? 0 : (l == 1) ? 185600 : (l == 2) ? 232000 : 243600;

    float x = rz.x * (float)W + ox - 0.5f;
    float y = rz.y * (float)H + oy - 0.5f;
    float x0f = floorf(x), y0f = floorf(y);
    float lx = x - x0f, ly = y - y0f;
    int x0 = (int)x0f, y0 = (int)y0f;
    int x1 = x0 + 1, y1 = y0 + 1;

    float wx0 = 1.f - lx, wx1 = lx;
    if (!((x0 >= 0) & (x0 < W))) wx0 = 0.f;
    if (!((x1 >= 0) & (x1 < W))) wx1 = 0.f;
    float wy0 = (1.f - ly) * aw, wy1 = ly * aw;
    if (!((y0 >= 0) & (y0 < H))) wy0 = 0.f;
    if (!((y1 >= 0) & (y1 < H))) wy1 = 0.f;

    int px  = min(max(x0, 0), W - 2);
    int x0c = min(max(x0, 0), W - 1);
    int x1c = min(max(x1, 0), W - 1);
    float wA = (x0c == px     ? wx0 : 0.f) + (x1c == px     ? wx1 : 0.f);
    float wB = (x0c == px + 1 ? wx0 : 0.f) + (x1c == px + 1 ? wx1 : 0.f);
    int y0c = min(max(y0, 0), H - 1);
    int y1c = min(max(y1, 0), H - 1);

    const int t0 = sub * 2, t1 = sub * 2 + 1;
    s_pidx[wv][h][t0]     = ub + (y0c * 8 + h) * W + px;
    s_wsel[wv][h][0][t0]  = wy0 * wA;
    s_wsel[wv][h][1][t0]  = wy0 * wB;
    s_pidx[wv][h][t1]     = ub + (y1c * 8 + h) * W + px;
    s_wsel[wv][h][0][t1]  = wy1 * wA;
    s_wsel[wv][h][1][t1]  = wy1 * wB;
  }
  __syncthreads();

  // --- phase 2: 8-lane cooperative 128B pair gathers ---
  const int colhalf = sub >> 2, e = sub & 3;
  const char* vbb = (const char*)vproj + (size_t)b * 15782400 + sub * 16;

  f32x2 acc0 = {0.f, 0.f}, acc1 = {0.f, 0.f}, acc2 = {0.f, 0.f}, acc3 = {0.f, 0.f};
#pragma unroll
  for (int t = 0; t < 16; ++t) {
    int pidx = s_pidx[wv][h][t];
    float w = s_wsel[wv][h][colhalf][t];
    uint4 v = *(const uint4*)(vbb + ((size_t)(unsigned)pidx << 6));
    f32x2 wvv = {w, w};
    f32x2 p0 = {__uint_as_float(v.x << 16), __uint_as_float(v.x & 0xffff0000u)};
    f32x2 p1 = {__uint_as_float(v.y << 16), __uint_as_float(v.y & 0xffff0000u)};
    f32x2 p2 = {__uint_as_float(v.z << 16), __uint_as_float(v.z & 0xffff0000u)};
    f32x2 p3 = {__uint_as_float(v.w << 16), __uint_as_float(v.w & 0xffff0000u)};
    acc0 += wvv * p0;
    acc1 += wvv * p1;
    acc2 += wvv * p2;
    acc3 += wvv * p3;
  }

  acc0.x += __shfl_xor(acc0.x, 4);  acc0.y += __shfl_xor(acc0.y, 4);
  acc1.x += __shfl_xor(acc1.x, 4);  acc1.y += __shfl_xor(acc1.y, 4);
  acc2.x += __shfl_xor(acc2.x, 4);  acc2.y += __shfl_xor(acc2.y, 4);
  acc3.x += __shfl_xor(acc3.x, 4);  acc3.y += __shfl_xor(acc3.y, 4);

  if (!colhalf) {
    __half2 h0, h1, h2, h3;
    h0.x = __float2half_rn(acc0.x); h0.y = __float2half_rn(acc0.y);
    h1.x = __float2half_rn(acc1.x); h1.y = __float2half_rn(acc1.y);
    h2.x = __float2half_rn(acc2.x); h2.y = __float2half_rn(acc2.y);
    h3.x = __float2half_rn(acc3.x); h3.y = __float2half_rn(acc3.y);
    uint4 w;
    w.x = *(unsigned*)&h0; w.y = *(unsigned*)&h1;
    w.z = *(unsigned*)&h2; w.w = *(unsigned*)&h3;
    *(uint4*)(partial + (size_t)item * 256 + h * 32 + e * 8) = w;
  }
}

// ---------------------------------------------------------------------------
// Stage B: out[bq][c] = sum_z partial[bq*4+z][c].  Fully streaming.
// ---------------------------------------------------------------------------
__global__ __launch_bounds__(256) void combine_kernel(
    const __half* __restrict__ partial, float* __restrict__ out) {
  int i = blockIdx.x * 256 + threadIdx.x;   // i in [0, 60000*128)
  if (i >= BS * NQ * 128) return;
  int bq = i >> 7, cp = i & 127;
  const __half2* p = (const __half2*)(partial + (size_t)bq * 1024) + cp;
  __half2 a0 = p[0], a1 = p[128], a2 = p[256], a3 = p[384];
  float sx = __half2float(a0.x) + __half2float(a1.x) +
             __half2float(a2.x) + __half2float(a3.x);
  float sy = __half2float(a0.y) + __half2float(a1.y) +
             __half2float(a2.y) + __half2float(a3.y);
  ((float2*)out)[i] = make_float2(sx, sy);
}

extern "C" void kernel_launch(void* const* d_in, const int* in_sizes, int n_in,
                              void* d_out, int out_size, void* d_ws, size_t ws_size,
                              hipStream_t stream) {
  const float* query  = (const float*)d_in[0];
  const float* value  = (const float*)d_in[1];
  const float* refp   = (const float*)d_in[2];
  const float* w_off  = (const float*)d_in[3];
  const float* b_off  = (const float*)d_in[4];
  const float* w_attn = (const float*)d_in[5];
  const float* b_attn = (const float*)d_in[6];
  const float* w_val  = (const float*)d_in[7];
  const float* b_val  = (const float*)d_in[8];
  float* out = (float*)d_out;

  char* ws = (char*)d_ws;
  // layout (bytes):
  //   vproj   bf16 level-blocked  @ 0           (94,694,400)
  //   C2      bf16 [60000*768]    @ 94,694,400  (92,160,000)
  //   wvalT   bf16 [256*256]      @ 186,854,400 (131,072)
  //   wpackT  bf16 [768*256]      @ 186,985,472 (393,216)
  //   bpack   f32  [768]          @ 187,378,688 (3,072)
  //   perm    u32  [240000]       @ 187,381,760 (960,000)
  //   hist    u32  [1536]         @ 188,341,760 (6,144)
  //   partial f16  [240000*256]   @ 188,347,904 (122,880,000) -> end 311,227,904
  unsigned short* vproj  = (unsigned short*)(ws);
  unsigned short* C2     = (unsigned short*)(ws + 94694400);
  unsigned short* wvalT  = (unsigned short*)(ws + 186854400);
  unsigned short* wpackT = (unsigned short*)(ws + 186985472);
  float*          bpack  = (float*)        (ws + 187378688);
  unsigned*       perm   = (unsigned*)     (ws + 187381760);
  unsigned*       hist   = (unsigned*)     (ws + 188341760);
  __half*         partial= (__half*)       (ws + 188347904);

  const int Mv = BS * NV;  // 184950
  const int Mq = BS * NQ;  // 60000
  const int NITEMS = BS * NQ * 4;  // 240000

  hipMemsetAsync(hist, 0, 1536 * 4, stream);
  prep_hist_kernel<<<1965, 256, 0, stream>>>(w_val, w_off, w_attn, b_off, b_attn,
                                             wvalT, wpackT, bpack, refp, hist);
  scan_kernel<<<1, 256, 0, stream>>>(hist);
  cell_scatter_kernel<<<(NITEMS + 255) / 256, 256, 0, stream>>>(refp, hist, perm);

  // value GEMM: N=256, NT=2 -> grid.y=1 (A read once)
  gemm_mfma_kernel<2, true><<<dim3((Mv + 127) / 128, 1), 256, 0, stream>>>(
      value, wvalT, b_val, vproj, Mv, 256);
  // query GEMM: N=768, NT=2 -> grid.y=3 (A read 3x instead of 6x)
  gemm_mfma_kernel<2, false><<<dim3((Mq + 127) / 128, 3), 256, 0, stream>>>(
      query, wpackT, bpack, C2, Mq, 768);

  msda_sample_kernel<<<60000, 256, 0, stream>>>(
      (const __hip_bfloat16*)vproj, (const __hip_bfloat16*)C2, refp, perm, partial);
  combine_kernel<<<(BS * NQ * 128 + 255) / 256, 256, 0, stream>>>(partial, out);
}

// Round 9
// 421.115 us; speedup vs baseline: 1.2481x; 1.2481x over previous
//
#include <hip/hip_runtime.h>
#include <hip/hip_bf16.h>

#define NQ 10000
#define BS 6
#define NV 30825   // 23200 + 5800 + 1450 + 375

typedef __attribute__((ext_vector_type(8))) short bf16x8;
typedef __attribute__((ext_vector_type(4))) float f32x4;

__device__ __forceinline__ void gload_lds16(const void* g, void* l) {
  __builtin_amdgcn_global_load_lds(
      (const __attribute__((address_space(1))) unsigned int*)g,
      (__attribute__((address_space(3))) unsigned int*)l, 16, 0, 0);
}

__device__ __forceinline__ unsigned short bf_bits(float f) {
  __hip_bfloat16 h = __float2bfloat16(f);
  return *(unsigned short*)&h;
}

// ---------------------------------------------------------------------------
// f32 -> bf16 conversion, 4 elems/thread
// ---------------------------------------------------------------------------
__global__ __launch_bounds__(256) void f32_to_bf16_kernel(
    const float* __restrict__ in, unsigned short* __restrict__ out, int n4) {
  int i = blockIdx.x * 256 + threadIdx.x;
  if (i >= n4) return;
  float4 v = ((const float4*)in)[i];
  ushort4 o;
  o.x = bf_bits(v.x); o.y = bf_bits(v.y); o.z = bf_bits(v.z); o.w = bf_bits(v.w);
  ((ushort4*)out)[i] = o;
}

// ---------------------------------------------------------------------------
// Pack + transpose weights to bf16:
//   wvalT [256][256]  = w_val^T
//   wpackT[768][256]  = concat(w_off, w_attn)^T
//   bpack [768]       = concat(b_off, b_attn)
// ---------------------------------------------------------------------------
__global__ __launch_bounds__(256) void prep_weights_kernel(
    const float* __restrict__ w_val, const float* __restrict__ w_off,
    const float* __restrict__ w_attn, const float* __restrict__ b_off,
    const float* __restrict__ b_attn, unsigned short* __restrict__ wvalT,
    unsigned short* __restrict__ wpackT, float* __restrict__ bpack) {
  int i = blockIdx.x * 256 + threadIdx.x;
  if (i < 65536) {
    int n = i >> 8, k = i & 255;
    wvalT[i] = bf_bits(w_val[k * 256 + n]);
  } else if (i < 65536 + 196608) {
    int j = i - 65536;
    int n = j >> 8, k = j & 255;
    float v = (n < 512) ? w_off[k * 512 + n] : w_attn[k * 256 + (n - 512)];
    wpackT[j] = bf_bits(v);
  } else if (i < 65536 + 196608 + 768) {
    int j = i - 262144;
    bpack[j] = (j < 512) ? b_off[j] : b_attn[j - 512];
  }
}

// ---------------------------------------------------------------------------
// MFMA GEMM: C[M,N](bf16) = A[M,256](bf16) @ WT[N,256]^T(bf16) + bias[N](f32)
// 128x128 tile, BK=64, 4 waves (2x2 of 64x64), global_load_lds width 16.
// Requires N % 128 == 0.
// ---------------------------------------------------------------------------
__global__ __launch_bounds__(256) void gemm_mfma_kernel(
    const unsigned short* __restrict__ A, const unsigned short* __restrict__ WT,
    const float* __restrict__ bias, unsigned short* __restrict__ C, int M, int N) {
  __shared__ short As[128 * 64];  // [row][k] 128B rows
  __shared__ short Bs[128 * 64];  // [col][k] 128B rows (WT layout)
  const int tid = threadIdx.x;
  const int wv = tid >> 6;
  const int lane = tid & 63;
  const int wr = wv >> 1, wc = wv & 1;
  const int m0 = blockIdx.x * 128;
  const int n0 = blockIdx.y * 128;

  f32x4 acc[4][4] = {};

  for (int kt = 0; kt < 4; ++kt) {
#pragma unroll
    for (int j = 0; j < 4; ++j) {
      int u = j * 256 + tid;
      int row = u >> 3;
      int kbyte = (u & 7) * 16;
      int ldsoff = (j * 256 + wv * 64) * 16;  // wave-uniform base (bytes)
      // A tile
      int gr = m0 + row; if (gr >= M) gr = M - 1;
      gload_lds16((const char*)A + (size_t)gr * 512 + kt * 128 + kbyte,
                  (char*)As + ldsoff);
      // B tile (WT rows are output cols)
      gload_lds16((const char*)WT + (size_t)(n0 + row) * 512 + kt * 128 + kbyte,
                  (char*)Bs + ldsoff);
    }
    __syncthreads();
#pragma unroll
    for (int kk = 0; kk < 2; ++kk) {
      bf16x8 af[4], bfr[4];
#pragma unroll
      for (int mi = 0; mi < 4; ++mi) {
        int off = (wr * 64 + mi * 16 + (lane & 15)) * 64 + kk * 32 + (lane >> 4) * 8;
        af[mi] = *(const bf16x8*)&As[off];
      }
#pragma unroll
      for (int ni = 0; ni < 4; ++ni) {
        int off = (wc * 64 + ni * 16 + (lane & 15)) * 64 + kk * 32 + (lane >> 4) * 8;
        bfr[ni] = *(const bf16x8*)&Bs[off];
      }
#pragma unroll
      for (int mi = 0; mi < 4; ++mi)
#pragma unroll
        for (int ni = 0; ni < 4; ++ni)
          acc[mi][ni] = __builtin_amdgcn_mfma_f32_16x16x32_bf16(
              af[mi], bfr[ni], acc[mi][ni], 0, 0, 0);
    }
    __syncthreads();
  }

  const int colb = n0 + wc * 64 + (lane & 15);
  float bvn[4];
#pragma unroll
  for (int ni = 0; ni < 4; ++ni) bvn[ni] = bias[colb + ni * 16];
#pragma unroll
  for (int mi = 0; mi < 4; ++mi) {
#pragma unroll
    for (int r = 0; r < 4; ++r) {
      int row = m0 + wr * 64 + mi * 16 + (lane >> 4) * 4 + r;
      if (row < M) {
#pragma unroll
        for (int ni = 0; ni < 4; ++ni)
          C[(size_t)row * N + colb + ni * 16] = bf_bits(acc[mi][ni][r] + bvn[ni]);
      }
    }
  }
}

// ---------------------------------------------------------------------------
// Sampling kernel, phase-split:
//  phase 1: 256 threads = 256 (head,level,point) samples; softmax + bilinear
//           setup once per sample -> LDS (idx,weight) x 4 corners.
//  phase 2: 256 threads = 8 heads x 16 lanes x 2 half-point-sets; each lane
//           gathers bf162 (2 channels) for 16 samples x 4 corners.
// ---------------------------------------------------------------------------
__global__ __launch_bounds__(256) void msda_sample_kernel(
    const __hip_bfloat16* __restrict__ vproj,  // [BS*NV, 256]
    const __hip_bfloat16* __restrict__ C2,     // [BS*NQ, 768]: 512 off | 256 attn
    const float* __restrict__ ref,             // [BS*NQ, 4, 2]
    float* __restrict__ out) {                 // [BS*NQ, 256]
  const int bq = blockIdx.x;
  const int b = bq / NQ;
  const int tid = threadIdx.x;

  __shared__ float2 s_iw[256][4];  // [.x = idx bits, .y = weight]

  {  // ---- phase 1 ----
    const int lp = tid & 31;
    const int l = lp >> 3, p = lp & 7, z = p & 3;
    const __hip_bfloat162* offp = (const __hip_bfloat162*)(C2 + (size_t)bq * 768);
    __hip_bfloat162 ob = offp[tid];
    float ox = __bfloat162float(ob.x), oy = __bfloat162float(ob.y);
    float logit = __bfloat162float(C2[(size_t)bq * 768 + 512 + tid]);

    float mx = logit;
#pragma unroll
    for (int m = 16; m >= 1; m >>= 1) mx = fmaxf(mx, __shfl_xor(mx, m, 32));
    float e = __expf(logit - mx);
    float s = e;
#pragma unroll
    for (int m = 16; m >= 1; m >>= 1) s += __shfl_xor(s, m, 32);
    float aw = e / s;

    float2 rz = *(const float2*)(ref + (size_t)bq * 8 + z * 2);
    const int W = 200 >> l;
    const int H = (l == 3) ? 15 : (116 >> l);
    const int base = (l == 0) ? 0 : (l == 1) ? 23200 : (l == 2) ? 29000 : 30450;

    float x = rz.x * (float)W + ox - 0.5f;
    float y = rz.y * (float)H + oy - 0.5f;
    float x0f = floorf(x), y0f = floorf(y);
    float lx = x - x0f, ly = y - y0f;
    int x0 = (int)x0f, y0 = (int)y0f;
    int x1 = x0 + 1, y1 = y0 + 1;

    float w00 = (1.f - ly) * (1.f - lx) * aw;
    float w01 = (1.f - ly) * lx * aw;
    float w10 = ly * (1.f - lx) * aw;
    float w11 = ly * lx * aw;

    if (!((x0 >= 0) & (x0 < W))) { w00 = 0.f; w10 = 0.f; }
    if (!((x1 >= 0) & (x1 < W))) { w01 = 0.f; w11 = 0.f; }
    if (!((y0 >= 0) & (y0 < H))) { w00 = 0.f; w01 = 0.f; }
    if (!((y1 >= 0) & (y1 < H))) { w10 = 0.f; w11 = 0.f; }

    int x0c = min(max(x0, 0), W - 1);
    int x1c = min(max(x1, 0), W - 1);
    int y0c = min(max(y0, 0), H - 1);
    int y1c = min(max(y1, 0), H - 1);

    s_iw[tid][0] = make_float2(__int_as_float(base + y0c * W + x0c), w00);
    s_iw[tid][1] = make_float2(__int_as_float(base + y0c * W + x1c), w01);
    s_iw[tid][2] = make_float2(__int_as_float(base + y1c * W + x0c), w10);
    s_iw[tid][3] = make_float2(__int_as_float(base + y1c * W + x1c), w11);
  }
  __syncthreads();

  // ---- phase 2 ----
  const int h = tid >> 5;
  const int half = (tid >> 4) & 1;
  const int lane16 = tid & 15;
  const __hip_bfloat162* vb =
      (const __hip_bfloat162*)(vproj + (size_t)b * NV * 256 + h * 32 + lane16 * 2);
  float accx = 0.f, accy = 0.f;
  const int sbase = h * 32 + half * 16;
#pragma unroll 4
  for (int s = 0; s < 16; ++s) {
    int si = sbase + s;
#pragma unroll
    for (int corner = 0; corner < 4; ++corner) {
      float2 iw = s_iw[si][corner];
      int row = __float_as_int(iw.x);
      float w = iw.y;
      __hip_bfloat162 v = vb[(size_t)row * 128];
      accx = fmaf(w, __bfloat162float(v.x), accx);
      accy = fmaf(w, __bfloat162float(v.y), accy);
    }
  }
  accx += __shfl_xor(accx, 16);
  accy += __shfl_xor(accy, 16);
  if (!half) {
    *(float2*)(out + (size_t)bq * 256 + h * 32 + lane16 * 2) = make_float2(accx, accy);
  }
}

extern "C" void kernel_launch(void* const* d_in, const int* in_sizes, int n_in,
                              void* d_out, int out_size, void* d_ws, size_t ws_size,
                              hipStream_t stream) {
  const float* query  = (const float*)d_in[0];
  const float* value  = (const float*)d_in[1];
  const float* refp   = (const float*)d_in[2];
  const float* w_off  = (const float*)d_in[3];
  const float* b_off  = (const float*)d_in[4];
  const float* w_attn = (const float*)d_in[5];
  const float* b_attn = (const float*)d_in[6];
  const float* w_val  = (const float*)d_in[7];
  const float* b_val  = (const float*)d_in[8];
  float* out = (float*)d_out;

  char* ws = (char*)d_ws;
  // layout (bytes):
  //   vproj  bf16 [184950*256]            @ 0          (94,694,400)
  //   valb   bf16 [184950*256]            @ 94,694,400 (94,694,400)  -- dead after gemm_val
  //   C2     bf16 [60000*768]             @ 94,694,400 (92,160,000)  -- aliases valb
  //   qb     bf16 [60000*256]             @ 189,388,800 (30,720,000)
  //   wvalT  bf16 [256*256]               @ 220,108,800 (131,072)
  //   wpackT bf16 [768*256]               @ 220,239,872 (393,216)
  //   bpack  f32  [768]                   @ 220,633,088 (3,072)
  unsigned short* vproj  = (unsigned short*)(ws);
  unsigned short* valb   = (unsigned short*)(ws + 94694400);
  unsigned short* C2     = (unsigned short*)(ws + 94694400);
  unsigned short* qb     = (unsigned short*)(ws + 189388800);
  unsigned short* wvalT  = (unsigned short*)(ws + 220108800);
  unsigned short* wpackT = (unsigned short*)(ws + 220239872);
  float*          bpack  = (float*)        (ws + 220633088);

  const int Mv = BS * NV;  // 184950
  const int Mq = BS * NQ;  // 60000

  prep_weights_kernel<<<1032, 256, 0, stream>>>(w_val, w_off, w_attn, b_off, b_attn,
                                                wvalT, wpackT, bpack);
  f32_to_bf16_kernel<<<(Mv * 64 + 255) / 256, 256, 0, stream>>>(value, valb, Mv * 64);
  f32_to_bf16_kernel<<<(Mq * 64 + 255) / 256, 256, 0, stream>>>(query, qb, Mq * 64);
  gemm_mfma_kernel<<<dim3((Mv + 127) / 128, 2), 256, 0, stream>>>(
      valb, wvalT, b_val, vproj, Mv, 256);
  gemm_mfma_kernel<<<dim3((Mq + 127) / 128, 6), 256, 0, stream>>>(
      qb, wpackT, bpack, C2, Mq, 768);
  msda_sample_kernel<<<BS * NQ, 256, 0, stream>>>(
      (const __hip_bfloat16*)vproj, (const __hip_bfloat16*)C2, refp, out);
}

// Round 10
// 395.526 us; speedup vs baseline: 1.3288x; 1.0647x over previous
//
#include <hip/hip_runtime.h>
#include <hip/hip_bf16.h>

#define NQ 10000
#define BS 6
#define NV 30825   // 23200 + 5800 + 1450 + 375

typedef __attribute__((ext_vector_type(8))) short bf16x8;
typedef __attribute__((ext_vector_type(4))) float f32x4;
typedef __attribute__((ext_vector_type(2))) float f32x2;

__device__ __forceinline__ void gload_lds16(const void* g, void* l) {
  __builtin_amdgcn_global_load_lds(
      (const __attribute__((address_space(1))) unsigned int*)g,
      (__attribute__((address_space(3))) unsigned int*)l, 16, 0, 0);
}

__device__ __forceinline__ unsigned short bf_bits(float f) {
  __hip_bfloat16 h = __float2bfloat16(f);
  return *(unsigned short*)&h;
}

// ---------------------------------------------------------------------------
// f32 -> bf16 conversion, 4 elems/thread
// ---------------------------------------------------------------------------
__global__ __launch_bounds__(256) void f32_to_bf16_kernel(
    const float* __restrict__ in, unsigned short* __restrict__ out, int n4) {
  int i = blockIdx.x * 256 + threadIdx.x;
  if (i >= n4) return;
  float4 v = ((const float4*)in)[i];
  ushort4 o;
  o.x = bf_bits(v.x); o.y = bf_bits(v.y); o.z = bf_bits(v.z); o.w = bf_bits(v.w);
  ((ushort4*)out)[i] = o;
}

// ---------------------------------------------------------------------------
// Pack + transpose weights to bf16:
//   wvalT [256][256]  = w_val^T
//   wpackT[768][256]  = concat(w_off, w_attn)^T
//   bpack [768]       = concat(b_off, b_attn)
// ---------------------------------------------------------------------------
__global__ __launch_bounds__(256) void prep_weights_kernel(
    const float* __restrict__ w_val, const float* __restrict__ w_off,
    const float* __restrict__ w_attn, const float* __restrict__ b_off,
    const float* __restrict__ b_attn, unsigned short* __restrict__ wvalT,
    unsigned short* __restrict__ wpackT, float* __restrict__ bpack) {
  int i = blockIdx.x * 256 + threadIdx.x;
  if (i < 65536) {
    int n = i >> 8, k = i & 255;
    wvalT[i] = bf_bits(w_val[k * 256 + n]);
  } else if (i < 65536 + 196608) {
    int j = i - 65536;
    int n = j >> 8, k = j & 255;
    float v = (n < 512) ? w_off[k * 512 + n] : w_attn[k * 256 + (n - 512)];
    wpackT[j] = bf_bits(v);
  } else if (i < 65536 + 196608 + 768) {
    int j = i - 262144;
    bpack[j] = (j < 512) ? b_off[j] : b_attn[j - 512];
  }
}

// ---------------------------------------------------------------------------
// MFMA GEMM: C[M,N](bf16) = A[M,256](bf16) @ WT[N,256]^T(bf16) + bias[N](f32)
// 128x128 tile, BK=64, 4 waves (2x2 of 64x64), global_load_lds width 16.
// Requires N % 128 == 0.
// ---------------------------------------------------------------------------
__global__ __launch_bounds__(256) void gemm_mfma_kernel(
    const unsigned short* __restrict__ A, const unsigned short* __restrict__ WT,
    const float* __restrict__ bias, unsigned short* __restrict__ C, int M, int N) {
  __shared__ short As[128 * 64];  // [row][k] 128B rows
  __shared__ short Bs[128 * 64];  // [col][k] 128B rows (WT layout)
  const int tid = threadIdx.x;
  const int wv = tid >> 6;
  const int lane = tid & 63;
  const int wr = wv >> 1, wc = wv & 1;
  const int m0 = blockIdx.x * 128;
  const int n0 = blockIdx.y * 128;

  f32x4 acc[4][4] = {};

  for (int kt = 0; kt < 4; ++kt) {
#pragma unroll
    for (int j = 0; j < 4; ++j) {
      int u = j * 256 + tid;
      int row = u >> 3;
      int kbyte = (u & 7) * 16;
      int ldsoff = (j * 256 + wv * 64) * 16;  // wave-uniform base (bytes)
      // A tile
      int gr = m0 + row; if (gr >= M) gr = M - 1;
      gload_lds16((const char*)A + (size_t)gr * 512 + kt * 128 + kbyte,
                  (char*)As + ldsoff);
      // B tile (WT rows are output cols)
      gload_lds16((const char*)WT + (size_t)(n0 + row) * 512 + kt * 128 + kbyte,
                  (char*)Bs + ldsoff);
    }
    __syncthreads();
#pragma unroll
    for (int kk = 0; kk < 2; ++kk) {
      bf16x8 af[4], bfr[4];
#pragma unroll
      for (int mi = 0; mi < 4; ++mi) {
        int off = (wr * 64 + mi * 16 + (lane & 15)) * 64 + kk * 32 + (lane >> 4) * 8;
        af[mi] = *(const bf16x8*)&As[off];
      }
#pragma unroll
      for (int ni = 0; ni < 4; ++ni) {
        int off = (wc * 64 + ni * 16 + (lane & 15)) * 64 + kk * 32 + (lane >> 4) * 8;
        bfr[ni] = *(const bf16x8*)&Bs[off];
      }
#pragma unroll
      for (int mi = 0; mi < 4; ++mi)
#pragma unroll
        for (int ni = 0; ni < 4; ++ni)
          acc[mi][ni] = __builtin_amdgcn_mfma_f32_16x16x32_bf16(
              af[mi], bfr[ni], acc[mi][ni], 0, 0, 0);
    }
    __syncthreads();
  }

  const int colb = n0 + wc * 64 + (lane & 15);
  float bvn[4];
#pragma unroll
  for (int ni = 0; ni < 4; ++ni) bvn[ni] = bias[colb + ni * 16];
#pragma unroll
  for (int mi = 0; mi < 4; ++mi) {
#pragma unroll
    for (int r = 0; r < 4; ++r) {
      int row = m0 + wr * 64 + mi * 16 + (lane >> 4) * 4 + r;
      if (row < M) {
#pragma unroll
        for (int ni = 0; ni < 4; ++ni)
          C[(size_t)row * N + colb + ni * 16] = bf_bits(acc[mi][ni][r] + bvn[ni]);
      }
    }
  }
}

// ---------------------------------------------------------------------------
// Sampling kernel, phase-split:
//  phase 1: 256 threads = 256 (head,level,point) samples; softmax + bilinear
//           setup -> LDS int4 pairs: (rowbyte, w) x 2 corners per entry.
//           rowbyte is the precomputed byte offset of the pixel row (x512).
//  phase 2: 256 threads = 8 heads x 16 lanes x 2 half-point-sets; per lane
//           2 channels via 4B gathers, uniform-base + 32-bit voffset
//           addressing, packed f32x2 fma accumulate.
// ---------------------------------------------------------------------------
__global__ __launch_bounds__(256) void msda_sample_kernel(
    const __hip_bfloat16* __restrict__ vproj,  // [BS*NV, 256]
    const __hip_bfloat16* __restrict__ C2,     // [BS*NQ, 768]: 512 off | 256 attn
    const float* __restrict__ ref,             // [BS*NQ, 4, 2]
    float* __restrict__ out) {                 // [BS*NQ, 256]
  const int bq = blockIdx.x;
  const int b = bq / NQ;
  const int tid = threadIdx.x;

  // index map idx(si) = si + (si>>4) spreads the 4 per-wave si groups
  // (stride 16) across distinct banks; max idx = 255 + 15 = 270.
  __shared__ int4 s_iw4[2][271];   // [pair][idx]: (rb0, w0, rb1, w1)

  {  // ---- phase 1 ----
    const int lp = tid & 31;
    const int l = lp >> 3, p = lp & 7, z = p & 3;
    const __hip_bfloat162* offp = (const __hip_bfloat162*)(C2 + (size_t)bq * 768);
    __hip_bfloat162 ob = offp[tid];
    float ox = __bfloat162float(ob.x), oy = __bfloat162float(ob.y);
    float logit = __bfloat162float(C2[(size_t)bq * 768 + 512 + tid]);

    float mx = logit;
#pragma unroll
    for (int m = 16; m >= 1; m >>= 1) mx = fmaxf(mx, __shfl_xor(mx, m, 32));
    float e = __expf(logit - mx);
    float s = e;
#pragma unroll
    for (int m = 16; m >= 1; m >>= 1) s += __shfl_xor(s, m, 32);
    float aw = e / s;

    float2 rz = *(const float2*)(ref + (size_t)bq * 8 + z * 2);
    const int W = 200 >> l;
    const int H = (l == 3) ? 15 : (116 >> l);
    const int base = (l == 0) ? 0 : (l == 1) ? 23200 : (l == 2) ? 29000 : 30450;

    float x = rz.x * (float)W + ox - 0.5f;
    float y = rz.y * (float)H + oy - 0.5f;
    float x0f = floorf(x), y0f = floorf(y);
    float lx = x - x0f, ly = y - y0f;
    int x0 = (int)x0f, y0 = (int)y0f;
    int x1 = x0 + 1, y1 = y0 + 1;

    float w00 = (1.f - ly) * (1.f - lx) * aw;
    float w01 = (1.f - ly) * lx * aw;
    float w10 = ly * (1.f - lx) * aw;
    float w11 = ly * lx * aw;

    if (!((x0 >= 0) & (x0 < W))) { w00 = 0.f; w10 = 0.f; }
    if (!((x1 >= 0) & (x1 < W))) { w01 = 0.f; w11 = 0.f; }
    if (!((y0 >= 0) & (y0 < H))) { w00 = 0.f; w01 = 0.f; }
    if (!((y1 >= 0) & (y1 < H))) { w10 = 0.f; w11 = 0.f; }

    int x0c = min(max(x0, 0), W - 1);
    int x1c = min(max(x1, 0), W - 1);
    int y0c = min(max(y0, 0), H - 1);
    int y1c = min(max(y1, 0), H - 1);

    int rb00 = (base + y0c * W + x0c) << 9;
    int rb01 = (base + y0c * W + x1c) << 9;
    int rb10 = (base + y1c * W + x0c) << 9;
    int rb11 = (base + y1c * W + x1c) << 9;

    const int it = tid + (tid >> 4);
    s_iw4[0][it] = make_int4(rb00, __float_as_int(w00), rb01, __float_as_int(w01));
    s_iw4[1][it] = make_int4(rb10, __float_as_int(w10), rb11, __float_as_int(w11));
  }
  __syncthreads();

  // ---- phase 2 ----
  const int h = tid >> 5;
  const int half = (tid >> 4) & 1;
  const int lane16 = tid & 15;
  const unsigned laneoff = (unsigned)(h * 64 + lane16 * 4);
  const char* ubase = (const char*)vproj + (size_t)b * NV * 512;
  const int sbase = h * 32 + half * 16;
  const int sb2 = sbase + (sbase >> 4);   // idx-mapped base (s<16 adds no carry)

  f32x2 acc = {0.f, 0.f};
#pragma unroll 4
  for (int s = 0; s < 16; ++s) {
    int4 cA = s_iw4[0][sb2 + s];
    int4 cB = s_iw4[1][sb2 + s];
    unsigned v0 = *(const unsigned*)(ubase + (unsigned)(cA.x) + laneoff);
    unsigned v1 = *(const unsigned*)(ubase + (unsigned)(cA.z) + laneoff);
    unsigned v2 = *(const unsigned*)(ubase + (unsigned)(cB.x) + laneoff);
    unsigned v3 = *(const unsigned*)(ubase + (unsigned)(cB.z) + laneoff);
    f32x2 p0 = {__uint_as_float(v0 << 16), __uint_as_float(v0 & 0xffff0000u)};
    f32x2 p1 = {__uint_as_float(v1 << 16), __uint_as_float(v1 & 0xffff0000u)};
    f32x2 p2 = {__uint_as_float(v2 << 16), __uint_as_float(v2 & 0xffff0000u)};
    f32x2 p3 = {__uint_as_float(v3 << 16), __uint_as_float(v3 & 0xffff0000u)};
    acc += p0 * __int_as_float(cA.y);
    acc += p1 * __int_as_float(cA.w);
    acc += p2 * __int_as_float(cB.y);
    acc += p3 * __int_as_float(cB.w);
  }

  acc.x += __shfl_xor(acc.x, 16);
  acc.y += __shfl_xor(acc.y, 16);
  if (!half) {
    *(float2*)(out + (size_t)bq * 256 + h * 32 + lane16 * 2) =
        make_float2(acc.x, acc.y);
  }
}

extern "C" void kernel_launch(void* const* d_in, const int* in_sizes, int n_in,
                              void* d_out, int out_size, void* d_ws, size_t ws_size,
                              hipStream_t stream) {
  const float* query  = (const float*)d_in[0];
  const float* value  = (const float*)d_in[1];
  const float* refp   = (const float*)d_in[2];
  const float* w_off  = (const float*)d_in[3];
  const float* b_off  = (const float*)d_in[4];
  const float* w_attn = (const float*)d_in[5];
  const float* b_attn = (const float*)d_in[6];
  const float* w_val  = (const float*)d_in[7];
  const float* b_val  = (const float*)d_in[8];
  float* out = (float*)d_out;

  char* ws = (char*)d_ws;
  // layout (bytes):
  //   vproj  bf16 [184950*256]            @ 0          (94,694,400)
  //   valb   bf16 [184950*256]            @ 94,694,400 (94,694,400)  -- dead after gemm_val
  //   C2     bf16 [60000*768]             @ 94,694,400 (92,160,000)  -- aliases valb
  //   qb     bf16 [60000*256]             @ 189,388,800 (30,720,000)
  //   wvalT  bf16 [256*256]               @ 220,108,800 (131,072)
  //   wpackT bf16 [768*256]               @ 220,239,872 (393,216)
  //   bpack  f32  [768]                   @ 220,633,088 (3,072)
  unsigned short* vproj  = (unsigned short*)(ws);
  unsigned short* valb   = (unsigned short*)(ws + 94694400);
  unsigned short* C2     = (unsigned short*)(ws + 94694400);
  unsigned short* qb     = (unsigned short*)(ws + 189388800);
  unsigned short* wvalT  = (unsigned short*)(ws + 220108800);
  unsigned short* wpackT = (unsigned short*)(ws + 220239872);
  float*          bpack  = (float*)        (ws + 220633088);

  const int Mv = BS * NV;  // 184950
  const int Mq = BS * NQ;  // 60000

  prep_weights_kernel<<<1032, 256, 0, stream>>>(w_val, w_off, w_attn, b_off, b_attn,
                                                wvalT, wpackT, bpack);
  f32_to_bf16_kernel<<<(Mv * 64 + 255) / 256, 256, 0, stream>>>(value, valb, Mv * 64);
  f32_to_bf16_kernel<<<(Mq * 64 + 255) / 256, 256, 0, stream>>>(query, qb, Mq * 64);
  gemm_mfma_kernel<<<dim3((Mv + 127) / 128, 2), 256, 0, stream>>>(
      valb, wvalT, b_val, vproj, Mv, 256);
  gemm_mfma_kernel<<<dim3((Mq + 127) / 128, 6), 256, 0, stream>>>(
      qb, wpackT, bpack, C2, Mq, 768);
  msda_sample_kernel<<<BS * NQ, 256, 0, stream>>>(
      (const __hip_bfloat16*)vproj, (const __hip_bfloat16*)C2, refp, out);
}

// Round 12
// 377.059 us; speedup vs baseline: 1.3939x; 1.0490x over previous
//
#include <hip/hip_runtime.h>
#include <hip/hip_bf16.h>

#define NQ 10000
#define BS 6
#define NV 30825   // 23200 + 5800 + 1450 + 375

typedef __attribute__((ext_vector_type(8))) short bf16x8;
typedef __attribute__((ext_vector_type(8))) unsigned short u16x8;
typedef __attribute__((ext_vector_type(4))) float f32x4;
typedef __attribute__((ext_vector_type(2))) float f32x2;

__device__ __forceinline__ void gload_lds16(const void* g, void* l) {
  __builtin_amdgcn_global_load_lds(
      (const __attribute__((address_space(1))) unsigned int*)g,
      (__attribute__((address_space(3))) unsigned int*)l, 16, 0, 0);
}

__device__ __forceinline__ unsigned short bf_bits(float f) {
  __hip_bfloat16 h = __float2bfloat16(f);
  return *(unsigned short*)&h;
}

// ---------------------------------------------------------------------------
// Pack + transpose weights to bf16:
//   wvalT [256][256]  = w_val^T
//   wpackT[768][256]  = concat(w_off, w_attn)^T
//   bpack [768]       = concat(b_off, b_attn)
// ---------------------------------------------------------------------------
__global__ __launch_bounds__(256) void prep_weights_kernel(
    const float* __restrict__ w_val, const float* __restrict__ w_off,
    const float* __restrict__ w_attn, const float* __restrict__ b_off,
    const float* __restrict__ b_attn, unsigned short* __restrict__ wvalT,
    unsigned short* __restrict__ wpackT, float* __restrict__ bpack) {
  int i = blockIdx.x * 256 + threadIdx.x;
  if (i < 65536) {
    int n = i >> 8, k = i & 255;
    wvalT[i] = bf_bits(w_val[k * 256 + n]);
  } else if (i < 65536 + 196608) {
    int j = i - 65536;
    int n = j >> 8, k = j & 255;
    float v = (n < 512) ? w_off[k * 512 + n] : w_attn[k * 256 + (n - 512)];
    wpackT[j] = bf_bits(v);
  } else if (i < 65536 + 196608 + 768) {
    int j = i - 262144;
    bpack[j] = (j < 512) ? b_off[j] : b_attn[j - 512];
  }
}

// ---------------------------------------------------------------------------
// Fused-convert MFMA GEMM:
//   C[M,N](bf16) = bf16(A[M,256] f32) @ WT[N,256]^T(bf16) + bias[N](f32)
// 512 threads = 8 waves (2x4 of 64x64) -> 128x256 tile, BK=64.
// A: reg-staged f32->bf16 (4x float4 per thread), staged to LDS after the
//    post-compute barrier; next K-step's loads issued BEFORE compute.
// B: global_load_lds width 16, double-buffered (2x32KB).
//    B-tile unit decomposition: 256 rows x 8 chunks of 16B -> row = u>>3,
//    kbyte = (u&7)*16 (bug in round 10: u>>2/(u&3) left half of each LDS
//    row stale and read WT out of bounds).
// Requires N % 256 == 0.
// ---------------------------------------------------------------------------
__global__ __launch_bounds__(512) void gemm_fused_kernel(
    const float* __restrict__ A, const unsigned short* __restrict__ WT,
    const float* __restrict__ bias, unsigned short* __restrict__ C, int M, int N) {
  __shared__ short As[128 * 64];       // 16 KB
  __shared__ short Bs[2][256 * 64];    // 2 x 32 KB
  const int tid = threadIdx.x;
  const int wv = tid >> 6;
  const int lane = tid & 63;
  const int wr = wv >> 2, wc = wv & 3;
  const int m0 = blockIdx.x * 128;
  const int n0 = blockIdx.y * 256;

  const int arow = tid >> 2, aq = tid & 3;   // each thread: A[arow][aq*16..+16]
  f32x4 acc[4][4] = {};
  float4 ar0, ar1, ar2, ar3;

  auto loadA = [&](int kt) {
    int gr = m0 + arow; if (gr >= M) gr = M - 1;
    const float4* ap = (const float4*)(A + (size_t)gr * 256 + kt * 64 + aq * 16);
    ar0 = ap[0]; ar1 = ap[1]; ar2 = ap[2]; ar3 = ap[3];
  };
  auto writeA = [&]() {
    u16x8 p0 = { bf_bits(ar0.x), bf_bits(ar0.y), bf_bits(ar0.z), bf_bits(ar0.w),
                 bf_bits(ar1.x), bf_bits(ar1.y), bf_bits(ar1.z), bf_bits(ar1.w) };
    u16x8 p1 = { bf_bits(ar2.x), bf_bits(ar2.y), bf_bits(ar2.z), bf_bits(ar2.w),
                 bf_bits(ar3.x), bf_bits(ar3.y), bf_bits(ar3.z), bf_bits(ar3.w) };
    *(u16x8*)&As[arow * 64 + aq * 16] = p0;
    *(u16x8*)&As[arow * 64 + aq * 16 + 8] = p1;
  };
  auto stageB = [&](int kt, int buf) {
#pragma unroll
    for (int j = 0; j < 4; ++j) {
      int u = j * 512 + tid;
      int row = u >> 3;                       // 0..255
      int kbyte = (u & 7) * 16;               // 0..112
      int ldsoff = (j * 512 + wv * 64) * 16;  // wave-uniform base = u*16 - lane*16
      gload_lds16((const char*)WT + (size_t)(n0 + row) * 512 + kt * 128 + kbyte,
                  (char*)Bs[buf] + ldsoff);
    }
  };

  loadA(0);
  stageB(0, 0);
  writeA();
  __syncthreads();

  for (int kt = 0; kt < 4; ++kt) {
    if (kt < 3) { loadA(kt + 1); stageB(kt + 1, (kt + 1) & 1); }
    const short* bs = Bs[kt & 1];
#pragma unroll
    for (int kk = 0; kk < 2; ++kk) {
      bf16x8 af[4], bfr[4];
#pragma unroll
      for (int mi = 0; mi < 4; ++mi) {
        int off = (wr * 64 + mi * 16 + (lane & 15)) * 64 + kk * 32 + (lane >> 4) * 8;
        af[mi] = *(const bf16x8*)&As[off];
      }
#pragma unroll
      for (int ni = 0; ni < 4; ++ni) {
        int off = (wc * 64 + ni * 16 + (lane & 15)) * 64 + kk * 32 + (lane >> 4) * 8;
        bfr[ni] = *(const bf16x8*)&bs[off];
      }
#pragma unroll
      for (int mi = 0; mi < 4; ++mi)
#pragma unroll
        for (int ni = 0; ni < 4; ++ni)
          acc[mi][ni] = __builtin_amdgcn_mfma_f32_16x16x32_bf16(
              af[mi], bfr[ni], acc[mi][ni], 0, 0, 0);
    }
    if (kt < 3) {
      __syncthreads();   // As reads done; next Bs gloads drained
      writeA();          // As <- next K-step (regs already loaded)
      __syncthreads();   // new As visible
    }
  }

  const int colb = n0 + wc * 64 + (lane & 15);
  float bvn[4];
#pragma unroll
  for (int ni = 0; ni < 4; ++ni) bvn[ni] = bias[colb + ni * 16];
#pragma unroll
  for (int mi = 0; mi < 4; ++mi) {
#pragma unroll
    for (int r = 0; r < 4; ++r) {
      int row = m0 + wr * 64 + mi * 16 + (lane >> 4) * 4 + r;
      if (row < M) {
#pragma unroll
        for (int ni = 0; ni < 4; ++ni)
          C[(size_t)row * N + colb + ni * 16] = bf_bits(acc[mi][ni][r] + bvn[ni]);
      }
    }
  }
}

// ---------------------------------------------------------------------------
// Sampling kernel (round-9 structure, unchanged):
//  phase 1: 256 (h,l,p) samples -> LDS int4 pairs (rowbyte, w) x 2 corners.
//  phase 2: 8 heads x 16 lanes x 2 halves; 4B gathers via uniform-base +
//           32-bit voffset; packed f32x2 fma accumulate.
// ---------------------------------------------------------------------------
__global__ __launch_bounds__(256) void msda_sample_kernel(
    const __hip_bfloat16* __restrict__ vproj,  // [BS*NV, 256]
    const __hip_bfloat16* __restrict__ C2,     // [BS*NQ, 768]: 512 off | 256 attn
    const float* __restrict__ ref,             // [BS*NQ, 4, 2]
    float* __restrict__ out) {                 // [BS*NQ, 256]
  const int bq = blockIdx.x;
  const int b = bq / NQ;
  const int tid = threadIdx.x;

  __shared__ int4 s_iw4[2][271];   // idx map si + (si>>4); (rb0,w0,rb1,w1)

  {  // ---- phase 1 ----
    const int lp = tid & 31;
    const int l = lp >> 3, p = lp & 7, z = p & 3;
    const __hip_bfloat162* offp = (const __hip_bfloat162*)(C2 + (size_t)bq * 768);
    __hip_bfloat162 ob = offp[tid];
    float ox = __bfloat162float(ob.x), oy = __bfloat162float(ob.y);
    float logit = __bfloat162float(C2[(size_t)bq * 768 + 512 + tid]);

    float mx = logit;
#pragma unroll
    for (int m = 16; m >= 1; m >>= 1) mx = fmaxf(mx, __shfl_xor(mx, m, 32));
    float e = __expf(logit - mx);
    float s = e;
#pragma unroll
    for (int m = 16; m >= 1; m >>= 1) s += __shfl_xor(s, m, 32);
    float aw = e / s;

    float2 rz = *(const float2*)(ref + (size_t)bq * 8 + z * 2);
    const int W = 200 >> l;
    const int H = (l == 3) ? 15 : (116 >> l);
    const int base = (l == 0) ? 0 : (l == 1) ? 23200 : (l == 2) ? 29000 : 30450;

    float x = rz.x * (float)W + ox - 0.5f;
    float y = rz.y * (float)H + oy - 0.5f;
    float x0f = floorf(x), y0f = floorf(y);
    float lx = x - x0f, ly = y - y0f;
    int x0 = (int)x0f, y0 = (int)y0f;
    int x1 = x0 + 1, y1 = y0 + 1;

    float w00 = (1.f - ly) * (1.f - lx) * aw;
    float w01 = (1.f - ly) * lx * aw;
    float w10 = ly * (1.f - lx) * aw;
    float w11 = ly * lx * aw;

    if (!((x0 >= 0) & (x0 < W))) { w00 = 0.f; w10 = 0.f; }
    if (!((x1 >= 0) & (x1 < W))) { w01 = 0.f; w11 = 0.f; }
    if (!((y0 >= 0) & (y0 < H))) { w00 = 0.f; w01 = 0.f; }
    if (!((y1 >= 0) & (y1 < H))) { w10 = 0.f; w11 = 0.f; }

    int x0c = min(max(x0, 0), W - 1);
    int x1c = min(max(x1, 0), W - 1);
    int y0c = min(max(y0, 0), H - 1);
    int y1c = min(max(y1, 0), H - 1);

    int rb00 = (base + y0c * W + x0c) << 9;
    int rb01 = (base + y0c * W + x1c) << 9;
    int rb10 = (base + y1c * W + x0c) << 9;
    int rb11 = (base + y1c * W + x1c) << 9;

    const int it = tid + (tid >> 4);
    s_iw4[0][it] = make_int4(rb00, __float_as_int(w00), rb01, __float_as_int(w01));
    s_iw4[1][it] = make_int4(rb10, __float_as_int(w10), rb11, __float_as_int(w11));
  }
  __syncthreads();

  // ---- phase 2 ----
  const int h = tid >> 5;
  const int half = (tid >> 4) & 1;
  const int lane16 = tid & 15;
  const unsigned laneoff = (unsigned)(h * 64 + lane16 * 4);
  const char* ubase = (const char*)vproj + (size_t)b * NV * 512;
  const int sbase = h * 32 + half * 16;
  const int sb2 = sbase + (sbase >> 4);

  f32x2 acc = {0.f, 0.f};
#pragma unroll 4
  for (int s = 0; s < 16; ++s) {
    int4 cA = s_iw4[0][sb2 + s];
    int4 cB = s_iw4[1][sb2 + s];
    unsigned v0 = *(const unsigned*)(ubase + (unsigned)(cA.x) + laneoff);
    unsigned v1 = *(const unsigned*)(ubase + (unsigned)(cA.z) + laneoff);
    unsigned v2 = *(const unsigned*)(ubase + (unsigned)(cB.x) + laneoff);
    unsigned v3 = *(const unsigned*)(ubase + (unsigned)(cB.z) + laneoff);
    f32x2 p0 = {__uint_as_float(v0 << 16), __uint_as_float(v0 & 0xffff0000u)};
    f32x2 p1 = {__uint_as_float(v1 << 16), __uint_as_float(v1 & 0xffff0000u)};
    f32x2 p2 = {__uint_as_float(v2 << 16), __uint_as_float(v2 & 0xffff0000u)};
    f32x2 p3 = {__uint_as_float(v3 << 16), __uint_as_float(v3 & 0xffff0000u)};
    acc += p0 * __int_as_float(cA.y);
    acc += p1 * __int_as_float(cA.w);
    acc += p2 * __int_as_float(cB.y);
    acc += p3 * __int_as_float(cB.w);
  }

  acc.x += __shfl_xor(acc.x, 16);
  acc.y += __shfl_xor(acc.y, 16);
  if (!half) {
    *(float2*)(out + (size_t)bq * 256 + h * 32 + lane16 * 2) =
        make_float2(acc.x, acc.y);
  }
}

extern "C" void kernel_launch(void* const* d_in, const int* in_sizes, int n_in,
                              void* d_out, int out_size, void* d_ws, size_t ws_size,
                              hipStream_t stream) {
  const float* query  = (const float*)d_in[0];
  const float* value  = (const float*)d_in[1];
  const float* refp   = (const float*)d_in[2];
  const float* w_off  = (const float*)d_in[3];
  const float* b_off  = (const float*)d_in[4];
  const float* w_attn = (const float*)d_in[5];
  const float* b_attn = (const float*)d_in[6];
  const float* w_val  = (const float*)d_in[7];
  const float* b_val  = (const float*)d_in[8];
  float* out = (float*)d_out;

  char* ws = (char*)d_ws;
  // layout (bytes):
  //   vproj  bf16 [184950*256]  @ 0           (94,694,400)
  //   C2     bf16 [60000*768]   @ 94,694,400  (92,160,000)
  //   wvalT  bf16 [256*256]     @ 186,854,400 (131,072)
  //   wpackT bf16 [768*256]     @ 186,985,472 (393,216)
  //   bpack  f32  [768]         @ 187,378,688 (3,072)   -> end 187,381,760
  unsigned short* vproj  = (unsigned short*)(ws);
  unsigned short* C2     = (unsigned short*)(ws + 94694400);
  unsigned short* wvalT  = (unsigned short*)(ws + 186854400);
  unsigned short* wpackT = (unsigned short*)(ws + 186985472);
  float*          bpack  = (float*)        (ws + 187378688);

  const int Mv = BS * NV;  // 184950
  const int Mq = BS * NQ;  // 60000

  prep_weights_kernel<<<1032, 256, 0, stream>>>(w_val, w_off, w_attn, b_off, b_attn,
                                                wvalT, wpackT, bpack);
  // value GEMM: N=256, grid.y=1 -> value read exactly once (fused convert)
  gemm_fused_kernel<<<dim3((Mv + 127) / 128, 1), 512, 0, stream>>>(
      value, wvalT, b_val, vproj, Mv, 256);
  // query GEMM: N=768, grid.y=3 (vs 6 before)
  gemm_fused_kernel<<<dim3((Mq + 127) / 128, 3), 512, 0, stream>>>(
      query, wpackT, bpack, C2, Mq, 768);
  msda_sample_kernel<<<BS * NQ, 256, 0, stream>>>(
      (const __hip_bfloat16*)vproj, (const __hip_bfloat16*)C2, refp, out);
}

// Round 13
// 373.108 us; speedup vs baseline: 1.4087x; 1.0106x over previous
//
#include <hip/hip_runtime.h>
#include <hip/hip_bf16.h>

#define NQ 10000
#define BS 6
#define NV 30825   // 23200 + 5800 + 1450 + 375

typedef __attribute__((ext_vector_type(8))) short bf16x8;
typedef __attribute__((ext_vector_type(8))) unsigned short u16x8;
typedef __attribute__((ext_vector_type(4))) float f32x4;
typedef __attribute__((ext_vector_type(2))) float f32x2;

__device__ __forceinline__ void gload_lds16(const void* g, void* l) {
  __builtin_amdgcn_global_load_lds(
      (const __attribute__((address_space(1))) unsigned int*)g,
      (__attribute__((address_space(3))) unsigned int*)l, 16, 0, 0);
}

__device__ __forceinline__ unsigned short bf_bits(float f) {
  __hip_bfloat16 h = __float2bfloat16(f);
  return *(unsigned short*)&h;
}

// ---------------------------------------------------------------------------
// Pack + transpose weights to bf16:
//   wvalT [256][256]  = w_val^T
//   wpackT[768][256]  = concat(w_off, w_attn)^T
//   bpack [768]       = concat(b_off, b_attn)
// ---------------------------------------------------------------------------
__global__ __launch_bounds__(256) void prep_weights_kernel(
    const float* __restrict__ w_val, const float* __restrict__ w_off,
    const float* __restrict__ w_attn, const float* __restrict__ b_off,
    const float* __restrict__ b_attn, unsigned short* __restrict__ wvalT,
    unsigned short* __restrict__ wpackT, float* __restrict__ bpack) {
  int i = blockIdx.x * 256 + threadIdx.x;
  if (i < 65536) {
    int n = i >> 8, k = i & 255;
    wvalT[i] = bf_bits(w_val[k * 256 + n]);
  } else if (i < 65536 + 196608) {
    int j = i - 65536;
    int n = j >> 8, k = j & 255;
    float v = (n < 512) ? w_off[k * 512 + n] : w_attn[k * 256 + (n - 512)];
    wpackT[j] = bf_bits(v);
  } else if (i < 65536 + 196608 + 768) {
    int j = i - 262144;
    bpack[j] = (j < 512) ? b_off[j] : b_attn[j - 512];
  }
}

// ---------------------------------------------------------------------------
// Fused-convert MFMA GEMM (round-11, unchanged):
//   C[M,N](bf16) = bf16(A[M,256] f32) @ WT[N,256]^T(bf16) + bias[N](f32)
// 512 threads = 8 waves (2x4 of 64x64) -> 128x256 tile, BK=64.
// ---------------------------------------------------------------------------
__global__ __launch_bounds__(512) void gemm_fused_kernel(
    const float* __restrict__ A, const unsigned short* __restrict__ WT,
    const float* __restrict__ bias, unsigned short* __restrict__ C, int M, int N) {
  __shared__ short As[128 * 64];       // 16 KB
  __shared__ short Bs[2][256 * 64];    // 2 x 32 KB
  const int tid = threadIdx.x;
  const int wv = tid >> 6;
  const int lane = tid & 63;
  const int wr = wv >> 2, wc = wv & 3;
  const int m0 = blockIdx.x * 128;
  const int n0 = blockIdx.y * 256;

  const int arow = tid >> 2, aq = tid & 3;   // each thread: A[arow][aq*16..+16]
  f32x4 acc[4][4] = {};
  float4 ar0, ar1, ar2, ar3;

  auto loadA = [&](int kt) {
    int gr = m0 + arow; if (gr >= M) gr = M - 1;
    const float4* ap = (const float4*)(A + (size_t)gr * 256 + kt * 64 + aq * 16);
    ar0 = ap[0]; ar1 = ap[1]; ar2 = ap[2]; ar3 = ap[3];
  };
  auto writeA = [&]() {
    u16x8 p0 = { bf_bits(ar0.x), bf_bits(ar0.y), bf_bits(ar0.z), bf_bits(ar0.w),
                 bf_bits(ar1.x), bf_bits(ar1.y), bf_bits(ar1.z), bf_bits(ar1.w) };
    u16x8 p1 = { bf_bits(ar2.x), bf_bits(ar2.y), bf_bits(ar2.z), bf_bits(ar2.w),
                 bf_bits(ar3.x), bf_bits(ar3.y), bf_bits(ar3.z), bf_bits(ar3.w) };
    *(u16x8*)&As[arow * 64 + aq * 16] = p0;
    *(u16x8*)&As[arow * 64 + aq * 16 + 8] = p1;
  };
  auto stageB = [&](int kt, int buf) {
#pragma unroll
    for (int j = 0; j < 4; ++j) {
      int u = j * 512 + tid;
      int row = u >> 3;                       // 0..255
      int kbyte = (u & 7) * 16;               // 0..112
      int ldsoff = (j * 512 + wv * 64) * 16;  // wave-uniform base = u*16 - lane*16
      gload_lds16((const char*)WT + (size_t)(n0 + row) * 512 + kt * 128 + kbyte,
                  (char*)Bs[buf] + ldsoff);
    }
  };

  loadA(0);
  stageB(0, 0);
  writeA();
  __syncthreads();

  for (int kt = 0; kt < 4; ++kt) {
    if (kt < 3) { loadA(kt + 1); stageB(kt + 1, (kt + 1) & 1); }
    const short* bs = Bs[kt & 1];
#pragma unroll
    for (int kk = 0; kk < 2; ++kk) {
      bf16x8 af[4], bfr[4];
#pragma unroll
      for (int mi = 0; mi < 4; ++mi) {
        int off = (wr * 64 + mi * 16 + (lane & 15)) * 64 + kk * 32 + (lane >> 4) * 8;
        af[mi] = *(const bf16x8*)&As[off];
      }
#pragma unroll
      for (int ni = 0; ni < 4; ++ni) {
        int off = (wc * 64 + ni * 16 + (lane & 15)) * 64 + kk * 32 + (lane >> 4) * 8;
        bfr[ni] = *(const bf16x8*)&bs[off];
      }
#pragma unroll
      for (int mi = 0; mi < 4; ++mi)
#pragma unroll
        for (int ni = 0; ni < 4; ++ni)
          acc[mi][ni] = __builtin_amdgcn_mfma_f32_16x16x32_bf16(
              af[mi], bfr[ni], acc[mi][ni], 0, 0, 0);
    }
    if (kt < 3) {
      __syncthreads();   // As reads done; next Bs gloads drained
      writeA();          // As <- next K-step (regs already loaded)
      __syncthreads();   // new As visible
    }
  }

  const int colb = n0 + wc * 64 + (lane & 15);
  float bvn[4];
#pragma unroll
  for (int ni = 0; ni < 4; ++ni) bvn[ni] = bias[colb + ni * 16];
#pragma unroll
  for (int mi = 0; mi < 4; ++mi) {
#pragma unroll
    for (int r = 0; r < 4; ++r) {
      int row = m0 + wr * 64 + mi * 16 + (lane >> 4) * 4 + r;
      if (row < M) {
#pragma unroll
        for (int ni = 0; ni < 4; ++ni)
          C[(size_t)row * N + colb + ni * 16] = bf_bits(acc[mi][ni][r] + bvn[ni]);
      }
    }
  }
}

// ---------------------------------------------------------------------------
// Sampling kernel (round-9 memory shape; inner gather loop FULLY unrolled to
// raise per-wave memory-level parallelism — the kernel is latency-chain
// bound, not VALU-bound: VALUBusy>100% readings were the gfx94x fallback
// formula, and pure-issue arithmetic gives ~80us vs 247us measured).
// ---------------------------------------------------------------------------
__global__ __launch_bounds__(256) void msda_sample_kernel(
    const __hip_bfloat16* __restrict__ vproj,  // [BS*NV, 256]
    const __hip_bfloat16* __restrict__ C2,     // [BS*NQ, 768]: 512 off | 256 attn
    const float* __restrict__ ref,             // [BS*NQ, 4, 2]
    float* __restrict__ out) {                 // [BS*NQ, 256]
  const int bq = blockIdx.x;
  const int b = bq / NQ;
  const int tid = threadIdx.x;

  __shared__ int4 s_iw4[2][271];   // idx map si + (si>>4); (rb0,w0,rb1,w1)

  {  // ---- phase 1 ----
    const int lp = tid & 31;
    const int l = lp >> 3, p = lp & 7, z = p & 3;
    const __hip_bfloat162* offp = (const __hip_bfloat162*)(C2 + (size_t)bq * 768);
    __hip_bfloat162 ob = offp[tid];
    float ox = __bfloat162float(ob.x), oy = __bfloat162float(ob.y);
    float logit = __bfloat162float(C2[(size_t)bq * 768 + 512 + tid]);

    float mx = logit;
#pragma unroll
    for (int m = 16; m >= 1; m >>= 1) mx = fmaxf(mx, __shfl_xor(mx, m, 32));
    float e = __expf(logit - mx);
    float s = e;
#pragma unroll
    for (int m = 16; m >= 1; m >>= 1) s += __shfl_xor(s, m, 32);
    float aw = e / s;

    float2 rz = *(const float2*)(ref + (size_t)bq * 8 + z * 2);
    const int W = 200 >> l;
    const int H = (l == 3) ? 15 : (116 >> l);
    const int base = (l == 0) ? 0 : (l == 1) ? 23200 : (l == 2) ? 29000 : 30450;

    float x = rz.x * (float)W + ox - 0.5f;
    float y = rz.y * (float)H + oy - 0.5f;
    float x0f = floorf(x), y0f = floorf(y);
    float lx = x - x0f, ly = y - y0f;
    int x0 = (int)x0f, y0 = (int)y0f;
    int x1 = x0 + 1, y1 = y0 + 1;

    float w00 = (1.f - ly) * (1.f - lx) * aw;
    float w01 = (1.f - ly) * lx * aw;
    float w10 = ly * (1.f - lx) * aw;
    float w11 = ly * lx * aw;

    if (!((x0 >= 0) & (x0 < W))) { w00 = 0.f; w10 = 0.f; }
    if (!((x1 >= 0) & (x1 < W))) { w01 = 0.f; w11 = 0.f; }
    if (!((y0 >= 0) & (y0 < H))) { w00 = 0.f; w01 = 0.f; }
    if (!((y1 >= 0) & (y1 < H))) { w10 = 0.f; w11 = 0.f; }

    int x0c = min(max(x0, 0), W - 1);
    int x1c = min(max(x1, 0), W - 1);
    int y0c = min(max(y0, 0), H - 1);
    int y1c = min(max(y1, 0), H - 1);

    int rb00 = (base + y0c * W + x0c) << 9;
    int rb01 = (base + y0c * W + x1c) << 9;
    int rb10 = (base + y1c * W + x0c) << 9;
    int rb11 = (base + y1c * W + x1c) << 9;

    const int it = tid + (tid >> 4);
    s_iw4[0][it] = make_int4(rb00, __float_as_int(w00), rb01, __float_as_int(w01));
    s_iw4[1][it] = make_int4(rb10, __float_as_int(w10), rb11, __float_as_int(w11));
  }
  __syncthreads();

  // ---- phase 2 ----
  const int h = tid >> 5;
  const int half = (tid >> 4) & 1;
  const int lane16 = tid & 15;
  const unsigned laneoff = (unsigned)(h * 64 + lane16 * 4);
  const char* ubase = (const char*)vproj + (size_t)b * NV * 512;
  const int sbase = h * 32 + half * 16;
  const int sb2 = sbase + (sbase >> 4);

  f32x2 acc = {0.f, 0.f};
#pragma unroll
  for (int s = 0; s < 16; ++s) {
    int4 cA = s_iw4[0][sb2 + s];
    int4 cB = s_iw4[1][sb2 + s];
    unsigned v0 = *(const unsigned*)(ubase + (unsigned)(cA.x) + laneoff);
    unsigned v1 = *(const unsigned*)(ubase + (unsigned)(cA.z) + laneoff);
    unsigned v2 = *(const unsigned*)(ubase + (unsigned)(cB.x) + laneoff);
    unsigned v3 = *(const unsigned*)(ubase + (unsigned)(cB.z) + laneoff);
    f32x2 p0 = {__uint_as_float(v0 << 16), __uint_as_float(v0 & 0xffff0000u)};
    f32x2 p1 = {__uint_as_float(v1 << 16), __uint_as_float(v1 & 0xffff0000u)};
    f32x2 p2 = {__uint_as_float(v2 << 16), __uint_as_float(v2 & 0xffff0000u)};
    f32x2 p3 = {__uint_as_float(v3 << 16), __uint_as_float(v3 & 0xffff0000u)};
    acc += p0 * __int_as_float(cA.y);
    acc += p1 * __int_as_float(cA.w);
    acc += p2 * __int_as_float(cB.y);
    acc += p3 * __int_as_float(cB.w);
  }

  acc.x += __shfl_xor(acc.x, 16);
  acc.y += __shfl_xor(acc.y, 16);
  if (!half) {
    *(float2*)(out + (size_t)bq * 256 + h * 32 + lane16 * 2) =
        make_float2(acc.x, acc.y);
  }
}

extern "C" void kernel_launch(void* const* d_in, const int* in_sizes, int n_in,
                              void* d_out, int out_size, void* d_ws, size_t ws_size,
                              hipStream_t stream) {
  const float* query  = (const float*)d_in[0];
  const float* value  = (const float*)d_in[1];
  const float* refp   = (const float*)d_in[2];
  const float* w_off  = (const float*)d_in[3];
  const float* b_off  = (const float*)d_in[4];
  const float* w_attn = (const float*)d_in[5];
  const float* b_attn = (const float*)d_in[6];
  const float* w_val  = (const float*)d_in[7];
  const float* b_val  = (const float*)d_in[8];
  float* out = (float*)d_out;

  char* ws = (char*)d_ws;
  // layout (bytes):
  //   vproj  bf16 [184950*256]  @ 0           (94,694,400)
  //   C2     bf16 [60000*768]   @ 94,694,400  (92,160,000)
  //   wvalT  bf16 [256*256]     @ 186,854,400 (131,072)
  //   wpackT bf16 [768*256]     @ 186,985,472 (393,216)
  //   bpack  f32  [768]         @ 187,378,688 (3,072)   -> end 187,381,760
  unsigned short* vproj  = (unsigned short*)(ws);
  unsigned short* C2     = (unsigned short*)(ws + 94694400);
  unsigned short* wvalT  = (unsigned short*)(ws + 186854400);
  unsigned short* wpackT = (unsigned short*)(ws + 186985472);
  float*          bpack  = (float*)        (ws + 187378688);

  const int Mv = BS * NV;  // 184950
  const int Mq = BS * NQ;  // 60000

  prep_weights_kernel<<<1032, 256, 0, stream>>>(w_val, w_off, w_attn, b_off, b_attn,
                                                wvalT, wpackT, bpack);
  // value GEMM: N=256, grid.y=1 -> value read exactly once (fused convert)
  gemm_fused_kernel<<<dim3((Mv + 127) / 128, 1), 512, 0, stream>>>(
      value, wvalT, b_val, vproj, Mv, 256);
  // query GEMM: N=768, grid.y=3
  gemm_fused_kernel<<<dim3((Mq + 127) / 128, 3), 512, 0, stream>>>(
      query, wpackT, bpack, C2, Mq, 768);
  msda_sample_kernel<<<BS * NQ, 256, 0, stream>>>(
      (const __hip_bfloat16*)vproj, (const __hip_bfloat16*)C2, refp, out);
}

// Round 14
// 371.804 us; speedup vs baseline: 1.4136x; 1.0035x over previous
//
#include <hip/hip_runtime.h>
#include <hip/hip_bf16.h>

#define NQ 10000
#define BS 6
#define NV 30825   // 23200 + 5800 + 1450 + 375

typedef __attribute__((ext_vector_type(8))) short bf16x8;
typedef __attribute__((ext_vector_type(8))) unsigned short u16x8;
typedef __attribute__((ext_vector_type(4))) float f32x4;
typedef __attribute__((ext_vector_type(2))) float f32x2;

__device__ __forceinline__ void gload_lds16(const void* g, void* l) {
  __builtin_amdgcn_global_load_lds(
      (const __attribute__((address_space(1))) unsigned int*)g,
      (__attribute__((address_space(3))) unsigned int*)l, 16, 0, 0);
}

__device__ __forceinline__ unsigned short bf_bits(float f) {
  __hip_bfloat16 h = __float2bfloat16(f);
  return *(unsigned short*)&h;
}

// ---------------------------------------------------------------------------
// Pack + transpose weights to bf16:
//   wvalT [256][256]  = w_val^T
//   wpackT[768][256]  = concat(w_off, w_attn)^T
//   bpack [768]       = concat(b_off, b_attn)
// ---------------------------------------------------------------------------
__global__ __launch_bounds__(256) void prep_weights_kernel(
    const float* __restrict__ w_val, const float* __restrict__ w_off,
    const float* __restrict__ w_attn, const float* __restrict__ b_off,
    const float* __restrict__ b_attn, unsigned short* __restrict__ wvalT,
    unsigned short* __restrict__ wpackT, float* __restrict__ bpack) {
  int i = blockIdx.x * 256 + threadIdx.x;
  if (i < 65536) {
    int n = i >> 8, k = i & 255;
    wvalT[i] = bf_bits(w_val[k * 256 + n]);
  } else if (i < 65536 + 196608) {
    int j = i - 65536;
    int n = j >> 8, k = j & 255;
    float v = (n < 512) ? w_off[k * 512 + n] : w_attn[k * 256 + (n - 512)];
    wpackT[j] = bf_bits(v);
  } else if (i < 65536 + 196608 + 768) {
    int j = i - 262144;
    bpack[j] = (j < 512) ? b_off[j] : b_attn[j - 512];
  }
}

// ---------------------------------------------------------------------------
// Fused-convert MFMA GEMM (round-11, unchanged):
//   C[M,N](bf16) = bf16(A[M,256] f32) @ WT[N,256]^T(bf16) + bias[N](f32)
// 512 threads = 8 waves (2x4 of 64x64) -> 128x256 tile, BK=64.
// ---------------------------------------------------------------------------
__global__ __launch_bounds__(512) void gemm_fused_kernel(
    const float* __restrict__ A, const unsigned short* __restrict__ WT,
    const float* __restrict__ bias, unsigned short* __restrict__ C, int M, int N) {
  __shared__ short As[128 * 64];       // 16 KB
  __shared__ short Bs[2][256 * 64];    // 2 x 32 KB
  const int tid = threadIdx.x;
  const int wv = tid >> 6;
  const int lane = tid & 63;
  const int wr = wv >> 2, wc = wv & 3;
  const int m0 = blockIdx.x * 128;
  const int n0 = blockIdx.y * 256;

  const int arow = tid >> 2, aq = tid & 3;   // each thread: A[arow][aq*16..+16]
  f32x4 acc[4][4] = {};
  float4 ar0, ar1, ar2, ar3;

  auto loadA = [&](int kt) {
    int gr = m0 + arow; if (gr >= M) gr = M - 1;
    const float4* ap = (const float4*)(A + (size_t)gr * 256 + kt * 64 + aq * 16);
    ar0 = ap[0]; ar1 = ap[1]; ar2 = ap[2]; ar3 = ap[3];
  };
  auto writeA = [&]() {
    u16x8 p0 = { bf_bits(ar0.x), bf_bits(ar0.y), bf_bits(ar0.z), bf_bits(ar0.w),
                 bf_bits(ar1.x), bf_bits(ar1.y), bf_bits(ar1.z), bf_bits(ar1.w) };
    u16x8 p1 = { bf_bits(ar2.x), bf_bits(ar2.y), bf_bits(ar2.z), bf_bits(ar2.w),
                 bf_bits(ar3.x), bf_bits(ar3.y), bf_bits(ar3.z), bf_bits(ar3.w) };
    *(u16x8*)&As[arow * 64 + aq * 16] = p0;
    *(u16x8*)&As[arow * 64 + aq * 16 + 8] = p1;
  };
  auto stageB = [&](int kt, int buf) {
#pragma unroll
    for (int j = 0; j < 4; ++j) {
      int u = j * 512 + tid;
      int row = u >> 3;                       // 0..255
      int kbyte = (u & 7) * 16;               // 0..112
      int ldsoff = (j * 512 + wv * 64) * 16;  // wave-uniform base = u*16 - lane*16
      gload_lds16((const char*)WT + (size_t)(n0 + row) * 512 + kt * 128 + kbyte,
                  (char*)Bs[buf] + ldsoff);
    }
  };

  loadA(0);
  stageB(0, 0);
  writeA();
  __syncthreads();

  for (int kt = 0; kt < 4; ++kt) {
    if (kt < 3) { loadA(kt + 1); stageB(kt + 1, (kt + 1) & 1); }
    const short* bs = Bs[kt & 1];
#pragma unroll
    for (int kk = 0; kk < 2; ++kk) {
      bf16x8 af[4], bfr[4];
#pragma unroll
      for (int mi = 0; mi < 4; ++mi) {
        int off = (wr * 64 + mi * 16 + (lane & 15)) * 64 + kk * 32 + (lane >> 4) * 8;
        af[mi] = *(const bf16x8*)&As[off];
      }
#pragma unroll
      for (int ni = 0; ni < 4; ++ni) {
        int off = (wc * 64 + ni * 16 + (lane & 15)) * 64 + kk * 32 + (lane >> 4) * 8;
        bfr[ni] = *(const bf16x8*)&bs[off];
      }
#pragma unroll
      for (int mi = 0; mi < 4; ++mi)
#pragma unroll
        for (int ni = 0; ni < 4; ++ni)
          acc[mi][ni] = __builtin_amdgcn_mfma_f32_16x16x32_bf16(
              af[mi], bfr[ni], acc[mi][ni], 0, 0, 0);
    }
    if (kt < 3) {
      __syncthreads();   // As reads done; next Bs gloads drained
      writeA();          // As <- next K-step (regs already loaded)
      __syncthreads();   // new As visible
    }
  }

  const int colb = n0 + wc * 64 + (lane & 15);
  float bvn[4];
#pragma unroll
  for (int ni = 0; ni < 4; ++ni) bvn[ni] = bias[colb + ni * 16];
#pragma unroll
  for (int mi = 0; mi < 4; ++mi) {
#pragma unroll
    for (int r = 0; r < 4; ++r) {
      int row = m0 + wr * 64 + mi * 16 + (lane >> 4) * 4 + r;
      if (row < M) {
#pragma unroll
        for (int ni = 0; ni < 4; ++ni)
          C[(size_t)row * N + colb + ni * 16] = bf_bits(acc[mi][ni][r] + bvn[ni]);
      }
    }
  }
}

// ---------------------------------------------------------------------------
// Sampling kernel. Phase 2 uses forced issue-then-consume: all 64 gathers
// load into an explicit vv[16][4] register array (compiler must keep 64
// loads in flight) before any accumulation. Weights re-read from LDS in the
// consume loop (cheap). All array indices compile-time after unroll.
// ---------------------------------------------------------------------------
__global__ __launch_bounds__(256) void msda_sample_kernel(
    const __hip_bfloat16* __restrict__ vproj,  // [BS*NV, 256]
    const __hip_bfloat16* __restrict__ C2,     // [BS*NQ, 768]: 512 off | 256 attn
    const float* __restrict__ ref,             // [BS*NQ, 4, 2]
    float* __restrict__ out) {                 // [BS*NQ, 256]
  const int bq = blockIdx.x;
  const int b = bq / NQ;
  const int tid = threadIdx.x;

  __shared__ int4 s_iw4[2][271];   // idx map si + (si>>4); (rb0,w0,rb1,w1)

  {  // ---- phase 1 ----
    const int lp = tid & 31;
    const int l = lp >> 3, p = lp & 7, z = p & 3;
    const __hip_bfloat162* offp = (const __hip_bfloat162*)(C2 + (size_t)bq * 768);
    __hip_bfloat162 ob = offp[tid];
    float ox = __bfloat162float(ob.x), oy = __bfloat162float(ob.y);
    float logit = __bfloat162float(C2[(size_t)bq * 768 + 512 + tid]);

    float mx = logit;
#pragma unroll
    for (int m = 16; m >= 1; m >>= 1) mx = fmaxf(mx, __shfl_xor(mx, m, 32));
    float e = __expf(logit - mx);
    float s = e;
#pragma unroll
    for (int m = 16; m >= 1; m >>= 1) s += __shfl_xor(s, m, 32);
    float aw = e / s;

    float2 rz = *(const float2*)(ref + (size_t)bq * 8 + z * 2);
    const int W = 200 >> l;
    const int H = (l == 3) ? 15 : (116 >> l);
    const int base = (l == 0) ? 0 : (l == 1) ? 23200 : (l == 2) ? 29000 : 30450;

    float x = rz.x * (float)W + ox - 0.5f;
    float y = rz.y * (float)H + oy - 0.5f;
    float x0f = floorf(x), y0f = floorf(y);
    float lx = x - x0f, ly = y - y0f;
    int x0 = (int)x0f, y0 = (int)y0f;
    int x1 = x0 + 1, y1 = y0 + 1;

    float w00 = (1.f - ly) * (1.f - lx) * aw;
    float w01 = (1.f - ly) * lx * aw;
    float w10 = ly * (1.f - lx) * aw;
    float w11 = ly * lx * aw;

    if (!((x0 >= 0) & (x0 < W))) { w00 = 0.f; w10 = 0.f; }
    if (!((x1 >= 0) & (x1 < W))) { w01 = 0.f; w11 = 0.f; }
    if (!((y0 >= 0) & (y0 < H))) { w00 = 0.f; w01 = 0.f; }
    if (!((y1 >= 0) & (y1 < H))) { w10 = 0.f; w11 = 0.f; }

    int x0c = min(max(x0, 0), W - 1);
    int x1c = min(max(x1, 0), W - 1);
    int y0c = min(max(y0, 0), H - 1);
    int y1c = min(max(y1, 0), H - 1);

    int rb00 = (base + y0c * W + x0c) << 9;
    int rb01 = (base + y0c * W + x1c) << 9;
    int rb10 = (base + y1c * W + x0c) << 9;
    int rb11 = (base + y1c * W + x1c) << 9;

    const int it = tid + (tid >> 4);
    s_iw4[0][it] = make_int4(rb00, __float_as_int(w00), rb01, __float_as_int(w01));
    s_iw4[1][it] = make_int4(rb10, __float_as_int(w10), rb11, __float_as_int(w11));
  }
  __syncthreads();

  // ---- phase 2 ----
  const int h = tid >> 5;
  const int half = (tid >> 4) & 1;
  const int lane16 = tid & 15;
  const unsigned laneoff = (unsigned)(h * 64 + lane16 * 4);
  const char* ubase = (const char*)vproj + (size_t)b * NV * 512;
  const int sbase = h * 32 + half * 16;
  const int sb2 = sbase + (sbase >> 4);

  // issue ALL 64 gathers before any consume
  unsigned vv[16][4];
#pragma unroll
  for (int s = 0; s < 16; ++s) {
    int4 cA = s_iw4[0][sb2 + s];
    int4 cB = s_iw4[1][sb2 + s];
    vv[s][0] = *(const unsigned*)(ubase + (unsigned)(cA.x) + laneoff);
    vv[s][1] = *(const unsigned*)(ubase + (unsigned)(cA.z) + laneoff);
    vv[s][2] = *(const unsigned*)(ubase + (unsigned)(cB.x) + laneoff);
    vv[s][3] = *(const unsigned*)(ubase + (unsigned)(cB.z) + laneoff);
  }

  f32x2 acc = {0.f, 0.f};
#pragma unroll
  for (int s = 0; s < 16; ++s) {
    int4 cA = s_iw4[0][sb2 + s];   // re-read for weights (LDS, cheap)
    int4 cB = s_iw4[1][sb2 + s];
    unsigned v0 = vv[s][0], v1 = vv[s][1], v2 = vv[s][2], v3 = vv[s][3];
    f32x2 p0 = {__uint_as_float(v0 << 16), __uint_as_float(v0 & 0xffff0000u)};
    f32x2 p1 = {__uint_as_float(v1 << 16), __uint_as_float(v1 & 0xffff0000u)};
    f32x2 p2 = {__uint_as_float(v2 << 16), __uint_as_float(v2 & 0xffff0000u)};
    f32x2 p3 = {__uint_as_float(v3 << 16), __uint_as_float(v3 & 0xffff0000u)};
    acc += p0 * __int_as_float(cA.y);
    acc += p1 * __int_as_float(cA.w);
    acc += p2 * __int_as_float(cB.y);
    acc += p3 * __int_as_float(cB.w);
  }

  acc.x += __shfl_xor(acc.x, 16);
  acc.y += __shfl_xor(acc.y, 16);
  if (!half) {
    *(float2*)(out + (size_t)bq * 256 + h * 32 + lane16 * 2) =
        make_float2(acc.x, acc.y);
  }
}

extern "C" void kernel_launch(void* const* d_in, const int* in_sizes, int n_in,
                              void* d_out, int out_size, void* d_ws, size_t ws_size,
                              hipStream_t stream) {
  const float* query  = (const float*)d_in[0];
  const float* value  = (const float*)d_in[1];
  const float* refp   = (const float*)d_in[2];
  const float* w_off  = (const float*)d_in[3];
  const float* b_off  = (const float*)d_in[4];
  const float* w_attn = (const float*)d_in[5];
  const float* b_attn = (const float*)d_in[6];
  const float* w_val  = (const float*)d_in[7];
  const float* b_val  = (const float*)d_in[8];
  float* out = (float*)d_out;

  char* ws = (char*)d_ws;
  // layout (bytes):
  //   vproj  bf16 [184950*256]  @ 0           (94,694,400)
  //   C2     bf16 [60000*768]   @ 94,694,400  (92,160,000)
  //   wvalT  bf16 [256*256]     @ 186,854,400 (131,072)
  //   wpackT bf16 [768*256]     @ 186,985,472 (393,216)
  //   bpack  f32  [768]         @ 187,378,688 (3,072)   -> end 187,381,760
  unsigned short* vproj  = (unsigned short*)(ws);
  unsigned short* C2     = (unsigned short*)(ws + 94694400);
  unsigned short* wvalT  = (unsigned short*)(ws + 186854400);
  unsigned short* wpackT = (unsigned short*)(ws + 186985472);
  float*          bpack  = (float*)        (ws + 187378688);

  const int Mv = BS * NV;  // 184950
  const int Mq = BS * NQ;  // 60000

  prep_weights_kernel<<<1032, 256, 0, stream>>>(w_val, w_off, w_attn, b_off, b_attn,
                                                wvalT, wpackT, bpack);
  // value GEMM: N=256, grid.y=1 -> value read exactly once (fused convert)
  gemm_fused_kernel<<<dim3((Mv + 127) / 128, 1), 512, 0, stream>>>(
      value, wvalT, b_val, vproj, Mv, 256);
  // query GEMM: N=768, grid.y=3
  gemm_fused_kernel<<<dim3((Mq + 127) / 128, 3), 512, 0, stream>>>(
      query, wpackT, bpack, C2, Mq, 768);
  msda_sample_kernel<<<BS * NQ, 256, 0, stream>>>(
      (const __hip_bfloat16*)vproj, (const __hip_bfloat16*)C2, refp, out);
}

// Round 15
// 371.775 us; speedup vs baseline: 1.4137x; 1.0001x over previous
//
#include <hip/hip_runtime.h>
#include <hip/hip_bf16.h>

#define NQ 10000
#define BS 6
#define NV 30825   // 23200 + 5800 + 1450 + 375

typedef __attribute__((ext_vector_type(8))) short bf16x8;
typedef __attribute__((ext_vector_type(8))) unsigned short u16x8;
typedef __attribute__((ext_vector_type(4))) float f32x4;
typedef __attribute__((ext_vector_type(2))) float f32x2;

__device__ __forceinline__ void gload_lds16(const void* g, void* l) {
  __builtin_amdgcn_global_load_lds(
      (const __attribute__((address_space(1))) unsigned int*)g,
      (__attribute__((address_space(3))) unsigned int*)l, 16, 0, 0);
}

__device__ __forceinline__ unsigned short bf_bits(float f) {
  __hip_bfloat16 h = __float2bfloat16(f);
  return *(unsigned short*)&h;
}

// ---------------------------------------------------------------------------
// Pack + transpose weights to bf16.
// ---------------------------------------------------------------------------
__global__ __launch_bounds__(256) void prep_weights_kernel(
    const float* __restrict__ w_val, const float* __restrict__ w_off,
    const float* __restrict__ w_attn, const float* __restrict__ b_off,
    const float* __restrict__ b_attn, unsigned short* __restrict__ wvalT,
    unsigned short* __restrict__ wpackT, float* __restrict__ bpack) {
  int i = blockIdx.x * 256 + threadIdx.x;
  if (i < 65536) {
    int n = i >> 8, k = i & 255;
    wvalT[i] = bf_bits(w_val[k * 256 + n]);
  } else if (i < 65536 + 196608) {
    int j = i - 65536;
    int n = j >> 8, k = j & 255;
    float v = (n < 512) ? w_off[k * 512 + n] : w_attn[k * 256 + (n - 512)];
    wpackT[j] = bf_bits(v);
  } else if (i < 65536 + 196608 + 768) {
    int j = i - 262144;
    bpack[j] = (j < 512) ? b_off[j] : b_attn[j - 512];
  }
}

// ---------------------------------------------------------------------------
// Fused-convert MFMA GEMM (round-11, unchanged).
// ---------------------------------------------------------------------------
__global__ __launch_bounds__(512) void gemm_fused_kernel(
    const float* __restrict__ A, const unsigned short* __restrict__ WT,
    const float* __restrict__ bias, unsigned short* __restrict__ C, int M, int N) {
  __shared__ short As[128 * 64];       // 16 KB
  __shared__ short Bs[2][256 * 64];    // 2 x 32 KB
  const int tid = threadIdx.x;
  const int wv = tid >> 6;
  const int lane = tid & 63;
  const int wr = wv >> 2, wc = wv & 3;
  const int m0 = blockIdx.x * 128;
  const int n0 = blockIdx.y * 256;

  const int arow = tid >> 2, aq = tid & 3;
  f32x4 acc[4][4] = {};
  float4 ar0, ar1, ar2, ar3;

  auto loadA = [&](int kt) {
    int gr = m0 + arow; if (gr >= M) gr = M - 1;
    const float4* ap = (const float4*)(A + (size_t)gr * 256 + kt * 64 + aq * 16);
    ar0 = ap[0]; ar1 = ap[1]; ar2 = ap[2]; ar3 = ap[3];
  };
  auto writeA = [&]() {
    u16x8 p0 = { bf_bits(ar0.x), bf_bits(ar0.y), bf_bits(ar0.z), bf_bits(ar0.w),
                 bf_bits(ar1.x), bf_bits(ar1.y), bf_bits(ar1.z), bf_bits(ar1.w) };
    u16x8 p1 = { bf_bits(ar2.x), bf_bits(ar2.y), bf_bits(ar2.z), bf_bits(ar2.w),
                 bf_bits(ar3.x), bf_bits(ar3.y), bf_bits(ar3.z), bf_bits(ar3.w) };
    *(u16x8*)&As[arow * 64 + aq * 16] = p0;
    *(u16x8*)&As[arow * 64 + aq * 16 + 8] = p1;
  };
  auto stageB = [&](int kt, int buf) {
#pragma unroll
    for (int j = 0; j < 4; ++j) {
      int u = j * 512 + tid;
      int row = u >> 3;                       // 0..255
      int kbyte = (u & 7) * 16;               // 0..112
      int ldsoff = (j * 512 + wv * 64) * 16;  // wave-uniform base = u*16 - lane*16
      gload_lds16((const char*)WT + (size_t)(n0 + row) * 512 + kt * 128 + kbyte,
                  (char*)Bs[buf] + ldsoff);
    }
  };

  loadA(0);
  stageB(0, 0);
  writeA();
  __syncthreads();

  for (int kt = 0; kt < 4; ++kt) {
    if (kt < 3) { loadA(kt + 1); stageB(kt + 1, (kt + 1) & 1); }
    const short* bs = Bs[kt & 1];
#pragma unroll
    for (int kk = 0; kk < 2; ++kk) {
      bf16x8 af[4], bfr[4];
#pragma unroll
      for (int mi = 0; mi < 4; ++mi) {
        int off = (wr * 64 + mi * 16 + (lane & 15)) * 64 + kk * 32 + (lane >> 4) * 8;
        af[mi] = *(const bf16x8*)&As[off];
      }
#pragma unroll
      for (int ni = 0; ni < 4; ++ni) {
        int off = (wc * 64 + ni * 16 + (lane & 15)) * 64 + kk * 32 + (lane >> 4) * 8;
        bfr[ni] = *(const bf16x8*)&bs[off];
      }
#pragma unroll
      for (int mi = 0; mi < 4; ++mi)
#pragma unroll
        for (int ni = 0; ni < 4; ++ni)
          acc[mi][ni] = __builtin_amdgcn_mfma_f32_16x16x32_bf16(
              af[mi], bfr[ni], acc[mi][ni], 0, 0, 0);
    }
    if (kt < 3) {
      __syncthreads();
      writeA();
      __syncthreads();
    }
  }

  const int colb = n0 + wc * 64 + (lane & 15);
  float bvn[4];
#pragma unroll
  for (int ni = 0; ni < 4; ++ni) bvn[ni] = bias[colb + ni * 16];
#pragma unroll
  for (int mi = 0; mi < 4; ++mi) {
#pragma unroll
    for (int r = 0; r < 4; ++r) {
      int row = m0 + wr * 64 + mi * 16 + (lane >> 4) * 4 + r;
      if (row < M) {
#pragma unroll
        for (int ni = 0; ni < 4; ++ni)
          C[(size_t)row * N + colb + ni * 16] = bf_bits(acc[mi][ni][r] + bvn[ni]);
      }
    }
  }
}

// ---------------------------------------------------------------------------
// Sampling kernel. Phase 2: INLINE-ASM forced-MLP gathers — 64 global_load
// (saddr form: 32-bit VGPR offset + SGPR base) issued back-to-back, one
// explicit s_waitcnt vmcnt(0) + sched_barrier, then unrolled consume.
// The compiler cannot re-serialize asm, so all 64 loads stay in flight.
// ---------------------------------------------------------------------------
__global__ __launch_bounds__(256) void msda_sample_kernel(
    const __hip_bfloat16* __restrict__ vproj,  // [BS*NV, 256]
    const __hip_bfloat16* __restrict__ C2,     // [BS*NQ, 768]: 512 off | 256 attn
    const float* __restrict__ ref,             // [BS*NQ, 4, 2]
    float* __restrict__ out) {                 // [BS*NQ, 256]
  const int bq = blockIdx.x;
  const int b = bq / NQ;
  const int tid = threadIdx.x;

  __shared__ int4 s_iw4[2][271];   // idx map si + (si>>4); (rb0,w0,rb1,w1)

  {  // ---- phase 1 ----
    const int lp = tid & 31;
    const int l = lp >> 3, p = lp & 7, z = p & 3;
    const __hip_bfloat162* offp = (const __hip_bfloat162*)(C2 + (size_t)bq * 768);
    __hip_bfloat162 ob = offp[tid];
    float ox = __bfloat162float(ob.x), oy = __bfloat162float(ob.y);
    float logit = __bfloat162float(C2[(size_t)bq * 768 + 512 + tid]);

    float mx = logit;
#pragma unroll
    for (int m = 16; m >= 1; m >>= 1) mx = fmaxf(mx, __shfl_xor(mx, m, 32));
    float e = __expf(logit - mx);
    float s = e;
#pragma unroll
    for (int m = 16; m >= 1; m >>= 1) s += __shfl_xor(s, m, 32);
    float aw = e / s;

    float2 rz = *(const float2*)(ref + (size_t)bq * 8 + z * 2);
    const int W = 200 >> l;
    const int H = (l == 3) ? 15 : (116 >> l);
    const int base = (l == 0) ? 0 : (l == 1) ? 23200 : (l == 2) ? 29000 : 30450;

    float x = rz.x * (float)W + ox - 0.5f;
    float y = rz.y * (float)H + oy - 0.5f;
    float x0f = floorf(x), y0f = floorf(y);
    float lx = x - x0f, ly = y - y0f;
    int x0 = (int)x0f, y0 = (int)y0f;
    int x1 = x0 + 1, y1 = y0 + 1;

    float w00 = (1.f - ly) * (1.f - lx) * aw;
    float w01 = (1.f - ly) * lx * aw;
    float w10 = ly * (1.f - lx) * aw;
    float w11 = ly * lx * aw;

    if (!((x0 >= 0) & (x0 < W))) { w00 = 0.f; w10 = 0.f; }
    if (!((x1 >= 0) & (x1 < W))) { w01 = 0.f; w11 = 0.f; }
    if (!((y0 >= 0) & (y0 < H))) { w00 = 0.f; w01 = 0.f; }
    if (!((y1 >= 0) & (y1 < H))) { w10 = 0.f; w11 = 0.f; }

    int x0c = min(max(x0, 0), W - 1);
    int x1c = min(max(x1, 0), W - 1);
    int y0c = min(max(y0, 0), H - 1);
    int y1c = min(max(y1, 0), H - 1);

    int rb00 = (base + y0c * W + x0c) << 9;
    int rb01 = (base + y0c * W + x1c) << 9;
    int rb10 = (base + y1c * W + x0c) << 9;
    int rb11 = (base + y1c * W + x1c) << 9;

    const int it = tid + (tid >> 4);
    s_iw4[0][it] = make_int4(rb00, __float_as_int(w00), rb01, __float_as_int(w01));
    s_iw4[1][it] = make_int4(rb10, __float_as_int(w10), rb11, __float_as_int(w11));
  }
  __syncthreads();

  // ---- phase 2 ----
  const int h = tid >> 5;
  const int half = (tid >> 4) & 1;
  const int lane16 = tid & 15;
  const unsigned laneoff = (unsigned)(h * 64 + lane16 * 4);
  const unsigned long long base64 =
      (unsigned long long)(const char*)vproj + (unsigned long long)b * (NV * 512ull);
  const int sbase = h * 32 + half * 16;
  const int sb2 = sbase + (sbase >> 4);

  // issue ALL 64 gathers via inline asm (compiler cannot sink these)
  unsigned vv[64];
#pragma unroll
  for (int s = 0; s < 16; ++s) {
    int4 cA = s_iw4[0][sb2 + s];
    int4 cB = s_iw4[1][sb2 + s];
    unsigned o0 = (unsigned)cA.x + laneoff;
    unsigned o1 = (unsigned)cA.z + laneoff;
    unsigned o2 = (unsigned)cB.x + laneoff;
    unsigned o3 = (unsigned)cB.z + laneoff;
    asm volatile("global_load_dword %0, %1, %2"
                 : "=v"(vv[4 * s + 0]) : "v"(o0), "s"(base64));
    asm volatile("global_load_dword %0, %1, %2"
                 : "=v"(vv[4 * s + 1]) : "v"(o1), "s"(base64));
    asm volatile("global_load_dword %0, %1, %2"
                 : "=v"(vv[4 * s + 2]) : "v"(o2), "s"(base64));
    asm volatile("global_load_dword %0, %1, %2"
                 : "=v"(vv[4 * s + 3]) : "v"(o3), "s"(base64));
  }
  asm volatile("s_waitcnt vmcnt(0)" ::: "memory");
  __builtin_amdgcn_sched_barrier(0);

  f32x2 acc = {0.f, 0.f};
#pragma unroll
  for (int s = 0; s < 16; ++s) {
    int4 cA = s_iw4[0][sb2 + s];   // re-read for weights (LDS, cheap)
    int4 cB = s_iw4[1][sb2 + s];
    unsigned v0 = vv[4 * s + 0], v1 = vv[4 * s + 1];
    unsigned v2 = vv[4 * s + 2], v3 = vv[4 * s + 3];
    f32x2 p0 = {__uint_as_float(v0 << 16), __uint_as_float(v0 & 0xffff0000u)};
    f32x2 p1 = {__uint_as_float(v1 << 16), __uint_as_float(v1 & 0xffff0000u)};
    f32x2 p2 = {__uint_as_float(v2 << 16), __uint_as_float(v2 & 0xffff0000u)};
    f32x2 p3 = {__uint_as_float(v3 << 16), __uint_as_float(v3 & 0xffff0000u)};
    acc += p0 * __int_as_float(cA.y);
    acc += p1 * __int_as_float(cA.w);
    acc += p2 * __int_as_float(cB.y);
    acc += p3 * __int_as_float(cB.w);
  }

  acc.x += __shfl_xor(acc.x, 16);
  acc.y += __shfl_xor(acc.y, 16);
  if (!half) {
    *(float2*)(out + (size_t)bq * 256 + h * 32 + lane16 * 2) =
        make_float2(acc.x, acc.y);
  }
}

extern "C" void kernel_launch(void* const* d_in, const int* in_sizes, int n_in,
                              void* d_out, int out_size, void* d_ws, size_t ws_size,
                              hipStream_t stream) {
  const float* query  = (const float*)d_in[0];
  const float* value  = (const float*)d_in[1];
  const float* refp   = (const float*)d_in[2];
  const float* w_off  = (const float*)d_in[3];
  const float* b_off  = (const float*)d_in[4];
  const float* w_attn = (const float*)d_in[5];
  const float* b_attn = (const float*)d_in[6];
  const float* w_val  = (const float*)d_in[7];
  const float* b_val  = (const float*)d_in[8];
  float* out = (float*)d_out;

  char* ws = (char*)d_ws;
  // layout (bytes):
  //   vproj  bf16 [184950*256]  @ 0           (94,694,400)
  //   C2     bf16 [60000*768]   @ 94,694,400  (92,160,000)
  //   wvalT  bf16 [256*256]     @ 186,854,400 (131,072)
  //   wpackT bf16 [768*256]     @ 186,985,472 (393,216)
  //   bpack  f32  [768]         @ 187,378,688 (3,072)   -> end 187,381,760
  unsigned short* vproj  = (unsigned short*)(ws);
  unsigned short* C2     = (unsigned short*)(ws + 94694400);
  unsigned short* wvalT  = (unsigned short*)(ws + 186854400);
  unsigned short* wpackT = (unsigned short*)(ws + 186985472);
  float*          bpack  = (float*)        (ws + 187378688);

  const int Mv = BS * NV;  // 184950
  const int Mq = BS * NQ;  // 60000

  prep_weights_kernel<<<1032, 256, 0, stream>>>(w_val, w_off, w_attn, b_off, b_attn,
                                                wvalT, wpackT, bpack);
  // value GEMM: N=256, grid.y=1 -> value read exactly once (fused convert)
  gemm_fused_kernel<<<dim3((Mv + 127) / 128, 1), 512, 0, stream>>>(
      value, wvalT, b_val, vproj, Mv, 256);
  // query GEMM: N=768, grid.y=3
  gemm_fused_kernel<<<dim3((Mq + 127) / 128, 3), 512, 0, stream>>>(
      query, wpackT, bpack, C2, Mq, 768);
  msda_sample_kernel<<<BS * NQ, 256, 0, stream>>>(
      (const __hip_bfloat16*)vproj, (const __hip_bfloat16*)C2, refp, out);
}